// Round 10
// baseline (215.963 us; speedup 1.0000x reference)
//
#include <hip/hip_runtime.h>
#include <hip/hip_bf16.h>

#define NN 50000
#define EE 800000
#define DD 128
#define HH 2
#define CC 128
#define HC 256
#define EDD 8

#define LEAKY 0.2f
#define SMEPS 1e-16f
#define LNEPS 1e-5f

#define SCAN_B 196   // ceil(NN/256)

// ---- ws byte offsets ----
#define HB_OFF    0u           // bf16 h interleaved [n][c][head]: NN*HC*2 = 25,600,000
#define ASRC_OFF  25600000u    // f32 a_src: NN*2*4 = 400,000
#define ADST_OFF  26000000u    // f32 a_dst         = 400,000
#define CONST_OFF 26400000u    // 530 floats (pad 4096)
#define SD_OFF    26404096u    // int2 sd: EE*8     = 6,400,000
#define RANK_OFF  32804096u    // int32 rank: EE*4  = 3,200,000
#define CNT_OFF   36004096u    // int32 cnt: 50176  = 200,704
#define ROW_OFF   36204800u    // int32 rowstart    = 200,704
#define PAY_OFF   36405504u    // int2 payload: EE*8= 6,400,000
#define WBT_OFF   42805504u    // bf16 wbT[256][128]= 65,536
#define BSUM_OFF  42871040u    // int32 bsum: 256
// total ~42.9 MB

typedef __attribute__((ext_vector_type(8))) short short8v;   // 8 bf16 (4 VGPR)
typedef __attribute__((ext_vector_type(4))) float float4v;   // MFMA acc
typedef __attribute__((ext_vector_type(2))) int int2v;       // NT-capable int2
typedef __attribute__((ext_vector_type(2))) float float2v;   // NT-capable float2

__device__ __forceinline__ float bf2f(unsigned short v) {
  return __uint_as_float(((unsigned)v) << 16);
}
__device__ __forceinline__ unsigned short f2bf(float f) {
  __hip_bfloat16 b = __float2bfloat16(f);
  return *reinterpret_cast<unsigned short*>(&b);
}

// K01: fused prep. Block 0: attention-projection collapse into consts.
// Blocks 1..128: W_lin -> bf16 transposed wbT. Blocks 129..324: zero cnt.
__global__ __launch_bounds__(256) void k01_prep(const float* __restrict__ W_lin,
                                                const float* __restrict__ att_src,
                                                const float* __restrict__ att_dst,
                                                const float* __restrict__ W_le,
                                                const float* __restrict__ att_edge,
                                                const float* __restrict__ W_ep,
                                                const float* __restrict__ b_ep,
                                                float* __restrict__ consts,
                                                unsigned short* __restrict__ wbT,
                                                int* __restrict__ cnt) {
  int b = blockIdx.x, tid = threadIdx.x;
  if (b == 0) {
    __shared__ float vlds[HH * DD];
    int h = tid >> 7, d = tid & 127;
    const float* as = att_src + h * CC;
    const float* ad = att_dst + h * CC;
    const float* ae = att_edge + h * CC;
    float us = 0.f, ud = 0.f, vv = 0.f;
    for (int c = 0; c < CC; ++c) {
      float wl = W_lin[d * HC + h * CC + c];
      float we = W_le[d * HC + h * CC + c];
      us += wl * as[c]; ud += wl * ad[c]; vv += we * ae[c];
    }
    consts[h * 128 + d] = us;
    consts[256 + h * 128 + d] = ud;
    vlds[h * 128 + d] = vv;
    __syncthreads();
    if (tid < 16) {
      int hh = tid >> 3, k = tid & 7;
      float w = 0.f;
      for (int dd2 = 0; dd2 < DD; ++dd2) w += W_ep[k * DD + dd2] * vlds[hh * 128 + dd2];
      consts[512 + hh * 8 + k] = w;
    }
    if (tid < 2) {
      float ce = 0.f;
      for (int dd2 = 0; dd2 < DD; ++dd2) ce += b_ep[dd2] * vlds[tid * 128 + dd2];
      consts[528 + tid] = ce;
    }
  } else if (b <= 128) {
    int i = (b - 1) * 256 + tid;           // i = k*256 + c, exactly 32768
    int k = i >> 8, c = i & 255;
    wbT[c * DD + k] = f2bf(W_lin[i]);
  } else {
    int n = (b - 129) * 256 + tid;
    if (n < NN) cnt[n] = 0;
  }
}

// K_convert: per-wave dtype detect + normalize to int2 sd[] + dst histogram.
// The histogram atomic's return value IS the edge's within-node rank.
__global__ __launch_bounds__(256) void k_convert(const int* __restrict__ ei_raw,
                                                 int2v* __restrict__ sd,
                                                 int* __restrict__ cnt,
                                                 int* __restrict__ rank) {
  // wave-uniform detect BEFORE any divergence: int64 iff 64 probe odd-words all 0
  int lane = threadIdx.x & 63;
  int probe = ei_raw[2 * lane + 1];
  bool is64 = (__ballot(probe != 0) == 0ull);
  int i = blockIdx.x * 256 + threadIdx.x;   // grid is exact: EE/256 = 3125
  int s, d;
  if (is64) { s = ei_raw[2 * i]; d = ei_raw[2 * (EE + i)]; }
  else      { s = ei_raw[i];     d = ei_raw[EE + i]; }
  int2v v; v.x = s; v.y = d;
  sd[i] = v;
  rank[i] = atomicAdd(&cnt[d], 1);
}

// K_scan1: per-block 256-wide exclusive scan of cnt -> rowstart (intra-block).
__global__ __launch_bounds__(256) void k_scan1(const int* __restrict__ cnt,
                                               int* __restrict__ rowstart,
                                               int* __restrict__ bsum) {
  __shared__ int sp[256];
  int t = threadIdx.x, b = blockIdx.x;
  int n = b * 256 + t;
  int v = (n < NN) ? cnt[n] : 0;
  sp[t] = v;
  __syncthreads();
  for (int off = 1; off < 256; off <<= 1) {
    int u = (t >= off) ? sp[t - off] : 0;
    __syncthreads();
    sp[t] += u;
    __syncthreads();
  }
  if (n < NN) rowstart[n] = sp[t] - v;
  if (t == 255) bsum[b] = sp[255];
}

// K_scan23: every block redundantly scans the 196 block sums in LDS, then
// applies its own block offset. Merges old phases 2+3 into one dispatch.
__global__ __launch_bounds__(256) void k_scan23(int* __restrict__ rowstart,
                                                const int* __restrict__ bsum) {
  __shared__ int sp[256];
  int t = threadIdx.x, b = blockIdx.x;
  int v = (t < SCAN_B) ? bsum[t] : 0;
  sp[t] = v;
  __syncthreads();
  for (int off = 1; off < 256; off <<= 1) {
    int u = (t >= off) ? sp[t - off] : 0;
    __syncthreads();
    sp[t] += u;
    __syncthreads();
  }
  int boff = (b == 0) ? 0 : sp[b - 1];   // exclusive prefix of block b
  int n = b * 256 + t;
  if (n < NN) rowstart[n] += boff;
  if (n == NN) rowstart[NN] = EE;        // b=195, t=80
}

// K2: h = x @ W_lin via MFMA 16x16x32 bf16. 64 rows x 256 cols, 4 waves.
// Epilogue restages through LDS -> coalesced 16B stores of head-interleaved hbuf.
__global__ __launch_bounds__(256) void k2_mfma(const float* __restrict__ x,
                                               const unsigned short* __restrict__ wbT,
                                               const float* __restrict__ consts,
                                               unsigned short* __restrict__ hbuf,
                                               float* __restrict__ a_src,
                                               float* __restrict__ a_dst) {
  __shared__ unsigned short xs[64 * 256];   // 32KB: staging uses first 16KB; epilogue all
  int tid = threadIdx.x;
  int n0 = blockIdx.x * 64;
  int r = tid >> 2, q = tid & 3;
  int n = n0 + r;
  bool valid = (n < NN);

  float xv[32];
  const float4* xp = (const float4*)(x + (size_t)n * DD + q * 32);
#pragma unroll
  for (int j = 0; j < 8; ++j) {
    float4 v = valid ? xp[j] : make_float4(0.f, 0.f, 0.f, 0.f);
    xv[j * 4 + 0] = v.x; xv[j * 4 + 1] = v.y; xv[j * 4 + 2] = v.z; xv[j * 4 + 3] = v.w;
  }
  float ps0 = 0.f, ps1 = 0.f, pd0 = 0.f, pd1 = 0.f;
#pragma unroll
  for (int j = 0; j < 32; j += 4) {
    float4 u0 = *(const float4*)(consts +   0 + q * 32 + j);
    float4 u1 = *(const float4*)(consts + 128 + q * 32 + j);
    float4 v0 = *(const float4*)(consts + 256 + q * 32 + j);
    float4 v1 = *(const float4*)(consts + 384 + q * 32 + j);
    ps0 += xv[j] * u0.x + xv[j+1] * u0.y + xv[j+2] * u0.z + xv[j+3] * u0.w;
    ps1 += xv[j] * u1.x + xv[j+1] * u1.y + xv[j+2] * u1.z + xv[j+3] * u1.w;
    pd0 += xv[j] * v0.x + xv[j+1] * v0.y + xv[j+2] * v0.z + xv[j+3] * v0.w;
    pd1 += xv[j] * v1.x + xv[j+1] * v1.y + xv[j+2] * v1.z + xv[j+3] * v1.w;
  }
#pragma unroll
  for (int off = 1; off < 4; off <<= 1) {
    ps0 += __shfl_xor(ps0, off); ps1 += __shfl_xor(ps1, off);
    pd0 += __shfl_xor(pd0, off); pd1 += __shfl_xor(pd1, off);
  }
  if (q == 0 && valid) {
    *(float2*)(a_src + n * 2) = make_float2(ps0, ps1);
    *(float2*)(a_dst + n * 2) = make_float2(pd0, pd1);
  }

  // bf16-convert + swizzled LDS staging write (first 16KB)
#pragma unroll
  for (int ci = 0; ci < 4; ++ci) {
    union { short8v v; unsigned short u[8]; } pk;
#pragma unroll
    for (int j = 0; j < 8; ++j) pk.u[j] = f2bf(xv[ci * 8 + j]);
    unsigned byte = r * 256 + (q * 4 + ci) * 16;
    byte ^= (r & 7) << 4;
    *(short8v*)((char*)xs + byte) = pk.v;
  }

  int wave = tid >> 6, l = tid & 63;
  int wc = wave * 64;
  int lr = l & 15, lg = l >> 4;
  short8v bfr[4][4];
#pragma unroll
  for (int ct = 0; ct < 4; ++ct) {
    int col = wc + ct * 16 + lr;
#pragma unroll
    for (int kt = 0; kt < 4; ++kt)
      bfr[ct][kt] = *(const short8v*)(wbT + (size_t)col * DD + kt * 32 + lg * 8);
  }

  __syncthreads();

  float4v acc[4][4];
#pragma unroll
  for (int rt = 0; rt < 4; ++rt)
#pragma unroll
    for (int ct = 0; ct < 4; ++ct) acc[rt][ct] = (float4v){0.f, 0.f, 0.f, 0.f};

#pragma unroll
  for (int kt = 0; kt < 4; ++kt) {
    short8v afr[4];
#pragma unroll
    for (int rt = 0; rt < 4; ++rt) {
      int row = rt * 16 + lr;
      unsigned byte = row * 256 + kt * 64 + lg * 16;
      byte ^= (row & 7) << 4;
      afr[rt] = *(const short8v*)((const char*)xs + byte);
    }
#pragma unroll
    for (int rt = 0; rt < 4; ++rt)
#pragma unroll
      for (int ct = 0; ct < 4; ++ct)
        acc[rt][ct] = __builtin_amdgcn_mfma_f32_16x16x32_bf16(afr[rt], bfr[ct][kt], acc[rt][ct], 0, 0, 0);
  }

  // ---- epilogue: acc -> LDS (interleaved layout, row-swizzled) -> 16B stores ----
  __syncthreads();   // all A-frag ds_reads complete before overwrite
#pragma unroll
  for (int rt = 0; rt < 4; ++rt) {
#pragma unroll
    for (int j = 0; j < 4; ++j) {
      int row = rt * 16 + lg * 4 + j;
#pragma unroll
      for (int ct = 0; ct < 4; ++ct) {
        int col = wc + ct * 16 + lr;
        int idx2 = ((col & 127) << 1) | (col >> 7);       // interleaved ushort index
        unsigned o = (unsigned)idx2 * 2;                  // byte within row [0,512)
        unsigned byte = row * 512 + (o ^ ((((unsigned)(row & 7) ^ ((o >> 7) & 3))) << 4));
        *(unsigned short*)((char*)xs + byte) = f2bf(acc[rt][ct][j]);
      }
    }
  }
  __syncthreads();
  {
    int r2 = tid >> 2, q2 = tid & 3;
    int n2 = n0 + r2;
    if (n2 < NN) {
#pragma unroll
      for (int k = 0; k < 8; ++k) {
        unsigned o = q2 * 128 + k * 16;
        unsigned byte = r2 * 512 + (o ^ ((((unsigned)(r2 & 7) ^ ((o >> 7) & 3))) << 4));
        short8v v = *(short8v*)((char*)xs + byte);
        *(short8v*)(hbuf + (size_t)n2 * HC + q2 * 64 + k * 8) = v;
      }
    }
  }
}

// K34: merged edge pass, ZERO atomics. score -> leaky -> ex=exp(score)
// (shift-invariant softmax; scores bounded ~|9| so fp32 exp is safe).
// payload[rowstart[d]+rank[e]] = {src*256, bf16(ex0)|bf16(ex1)<<16}, NT store.
__global__ __launch_bounds__(256) void k34_edge(const int2v* __restrict__ sd,
                                                const int* __restrict__ rank,
                                                const int* __restrict__ rowstart,
                                                const float* __restrict__ edge_attr,
                                                const float* __restrict__ a_src,
                                                const float* __restrict__ a_dst,
                                                const float* __restrict__ consts,
                                                int2v* __restrict__ payload) {
  int e = blockIdx.x * 256 + threadIdx.x;   // grid exact: EE/256
  int2v sdv = sd[e];
  int s = sdv.x, d = sdv.y;
  float4 ea0 = *(const float4*)(edge_attr + (size_t)e * 8);
  float4 ea1 = *(const float4*)(edge_attr + (size_t)e * 8 + 4);
  float2 asv = *(const float2*)(a_src + s * 2);
  float2 adv = *(const float2*)(a_dst + d * 2);
  const float* w0 = consts + 512;
  const float* w1 = consts + 520;
  float sc0 = asv.x + adv.x + consts[528]
            + ea0.x * w0[0] + ea0.y * w0[1] + ea0.z * w0[2] + ea0.w * w0[3]
            + ea1.x * w0[4] + ea1.y * w0[5] + ea1.z * w0[6] + ea1.w * w0[7];
  float sc1 = asv.y + adv.y + consts[529]
            + ea0.x * w1[0] + ea0.y * w1[1] + ea0.z * w1[2] + ea0.w * w1[3]
            + ea1.x * w1[4] + ea1.y * w1[5] + ea1.z * w1[6] + ea1.w * w1[7];
  sc0 = (sc0 >= 0.f) ? sc0 : LEAKY * sc0;
  sc1 = (sc1 >= 0.f) ? sc1 : LEAKY * sc1;
  float ex0 = __expf(sc0);
  float ex1 = __expf(sc1);
  unsigned pk = (unsigned)f2bf(ex0) | ((unsigned)f2bf(ex1) << 16);
  int pos = rowstart[d] + rank[e];
  int2v pv; pv.x = s << 8; pv.y = (int)pk;
  __builtin_nontemporal_store(pv, &payload[pos]);
}

// K5: wave per node. CSR walk, 2-deep payload / 1-deep gather pipeline.
// payload.x is pre-scaled (src*256). One ushort4 per lane per edge.
__global__ __launch_bounds__(256) void k5_fused(const int* __restrict__ rowstart,
                                                const int2v* __restrict__ payload,
                                                const unsigned short* __restrict__ hb2,
                                                const float* __restrict__ x,
                                                const float* __restrict__ bias,
                                                const float* __restrict__ gamma,
                                                const float* __restrict__ beta,
                                                float* __restrict__ out) {
  int n = blockIdx.x * 4 + (threadIdx.x >> 6);
  int lane = threadIdx.x & 63;
  if (n >= NN) return;
  int p0 = rowstart[n], p1 = rowstart[n + 1];
  int len = p1 - p0;
  int c0 = lane * 2;
  const int2v* pp = payload + p0;
  float a00 = 0.f, a01 = 0.f, a10 = 0.f, a11 = 0.f, se0 = 0.f, se1 = 0.f;

#define K5_LD(soff) (*(const ushort4*)(hb2 + (size_t)(unsigned)(soff) + lane * 4))
#define K5_ACC(pl, hv) { \
    float ex0 = bf2f((unsigned short)((unsigned)(pl).y & 0xffffu)); \
    float ex1 = bf2f((unsigned short)(((unsigned)(pl).y) >> 16)); \
    a00 = fmaf(ex0, bf2f((hv).x), a00); \
    a01 = fmaf(ex1, bf2f((hv).y), a01); \
    a10 = fmaf(ex0, bf2f((hv).z), a10); \
    a11 = fmaf(ex1, bf2f((hv).w), a11); \
    se0 += ex0; se1 += ex1; }

  if (len > 0) {
    int2v plA = __builtin_nontemporal_load(&pp[0]);
    int2v plB = (len > 1) ? __builtin_nontemporal_load(&pp[1]) : plA;
    ushort4 hA = K5_LD(plA.x);
    for (int i = 0; i + 2 < len; ++i) {
      int2v plC = __builtin_nontemporal_load(&pp[i + 2]);
      ushort4 hB = K5_LD(plB.x);
      K5_ACC(plA, hA);
      plA = plB; plB = plC; hA = hB;
    }
    if (len > 1) {
      ushort4 hB = K5_LD(plB.x);
      K5_ACC(plA, hA);
      plA = plB; hA = hB;
    }
    K5_ACC(plA, hA);
  }
#undef K5_LD
#undef K5_ACC

  float inv0 = 0.5f / (se0 + SMEPS);
  float inv1 = 0.5f / (se1 + SMEPS);
  float2v xv = __builtin_nontemporal_load((const float2v*)(x + (size_t)n * DD + c0));
  float v0 = a00 * inv0 + a01 * inv1 + bias[c0] + xv.x;
  float v1 = a10 * inv0 + a11 * inv1 + bias[c0 + 1] + xv.y;
  float s = v0 + v1, ss = v0 * v0 + v1 * v1;
#pragma unroll
  for (int o = 32; o > 0; o >>= 1) {
    s += __shfl_xor(s, o);
    ss += __shfl_xor(ss, o);
  }
  float mu = s * (1.f / 128.f);
  float var = ss * (1.f / 128.f) - mu * mu;
  float rstd = rsqrtf(var + LNEPS);
  float2v ov;
  ov.x = (v0 - mu) * rstd * gamma[c0] + beta[c0];
  ov.y = (v1 - mu) * rstd * gamma[c0 + 1] + beta[c0 + 1];
  __builtin_nontemporal_store(ov, (float2v*)(out + (size_t)n * CC + c0));
}

extern "C" void kernel_launch(void* const* d_in, const int* in_sizes, int n_in,
                              void* d_out, int out_size, void* d_ws, size_t ws_size,
                              hipStream_t stream) {
  const float* x        = (const float*)d_in[0];
  const int*   ei_raw   = (const int*)d_in[1];
  const float* edge_attr= (const float*)d_in[2];
  const float* W_ep     = (const float*)d_in[3];
  const float* b_ep     = (const float*)d_in[4];
  const float* W_lin    = (const float*)d_in[5];
  const float* att_src  = (const float*)d_in[6];
  const float* att_dst  = (const float*)d_in[7];
  const float* W_le     = (const float*)d_in[8];
  const float* att_edge = (const float*)d_in[9];
  const float* bias_gat = (const float*)d_in[10];
  const float* ln_gamma = (const float*)d_in[11];
  const float* ln_beta  = (const float*)d_in[12];

  char* ws = (char*)d_ws;
  unsigned short* hbuf = (unsigned short*)(ws + HB_OFF);
  float*    a_src  = (float*)(ws + ASRC_OFF);
  float*    a_dst  = (float*)(ws + ADST_OFF);
  float*    consts = (float*)(ws + CONST_OFF);
  int2v*    sd     = (int2v*)(ws + SD_OFF);
  int*      rank   = (int*)(ws + RANK_OFF);
  int*      cnt    = (int*)(ws + CNT_OFF);
  int*      rowst  = (int*)(ws + ROW_OFF);
  int2v*    payload= (int2v*)(ws + PAY_OFF);
  unsigned short* wbT = (unsigned short*)(ws + WBT_OFF);
  int*      bsum   = (int*)(ws + BSUM_OFF);

  k01_prep<<<325, 256, 0, stream>>>(W_lin, att_src, att_dst, W_le, att_edge, W_ep, b_ep,
                                    consts, wbT, cnt);
  k_convert<<<EE / 256, 256, 0, stream>>>(ei_raw, sd, cnt, rank);
  k_scan1<<<SCAN_B, 256, 0, stream>>>(cnt, rowst, bsum);
  k_scan23<<<SCAN_B, 256, 0, stream>>>(rowst, bsum);
  k2_mfma<<<(NN + 63) / 64, 256, 0, stream>>>(x, wbT, consts, hbuf, a_src, a_dst);
  k34_edge<<<EE / 256, 256, 0, stream>>>(sd, rank, rowst, edge_attr, a_src, a_dst, consts, payload);
  k5_fused<<<(NN + 3) / 4, 256, 0, stream>>>(rowst, payload, hbuf, x, bias_gat, ln_gamma, ln_beta, (float*)d_out);
}

// Round 11
// 188.459 us; speedup vs baseline: 1.1459x; 1.1459x over previous
//
#include <hip/hip_runtime.h>
#include <hip/hip_bf16.h>

#define NN 50000
#define EE 800000
#define DD 128
#define HH 2
#define CC 128
#define HC 256
#define EDD 8

#define LEAKY 0.2f
#define SMEPS 1e-16f
#define LNEPS 1e-5f

#define SCAN_B 196   // ceil(NN/256)

// ---- ws byte offsets ----
#define HB_OFF    0u           // bf16 h interleaved [n][c][head]: NN*HC*2 = 25,600,000
#define ASRC_OFF  25600000u    // f32 a_src: NN*2*4 = 400,000
#define ADST_OFF  26000000u    // f32 a_dst         = 400,000
#define CONST_OFF 26400000u    // 530 floats (pad 4096)
#define SD_OFF    26404096u    // int2 sd: EE*8     = 6,400,000
#define RANK_OFF  32804096u    // int32 rank: EE*4  = 3,200,000
#define CNT_OFF   36004096u    // int32 cnt: 50176  = 200,704
#define ROW_OFF   36204800u    // int32 rowstart    = 200,704
#define PAY_OFF   36405504u    // int2 payload: EE*8= 6,400,000
#define WBT_OFF   42805504u    // bf16 wbT[256][128]= 65,536
#define BSUM_OFF  42871040u    // int32 bsum: 256
// total ~42.9 MB

typedef __attribute__((ext_vector_type(8))) short short8v;   // 8 bf16 (4 VGPR)
typedef __attribute__((ext_vector_type(4))) float float4v;   // MFMA acc
typedef __attribute__((ext_vector_type(2))) int int2v;
typedef __attribute__((ext_vector_type(2))) float float2v;

__device__ __forceinline__ float bf2f(unsigned short v) {
  return __uint_as_float(((unsigned)v) << 16);
}
__device__ __forceinline__ unsigned short f2bf(float f) {
  __hip_bfloat16 b = __float2bfloat16(f);
  return *reinterpret_cast<unsigned short*>(&b);
}

// K01: fused prep. Block 0: attention-projection collapse into consts.
// Blocks 1..128: W_lin -> bf16 transposed wbT. Blocks 129..324: zero cnt.
__global__ __launch_bounds__(256) void k01_prep(const float* __restrict__ W_lin,
                                                const float* __restrict__ att_src,
                                                const float* __restrict__ att_dst,
                                                const float* __restrict__ W_le,
                                                const float* __restrict__ att_edge,
                                                const float* __restrict__ W_ep,
                                                const float* __restrict__ b_ep,
                                                float* __restrict__ consts,
                                                unsigned short* __restrict__ wbT,
                                                int* __restrict__ cnt) {
  int b = blockIdx.x, tid = threadIdx.x;
  if (b == 0) {
    __shared__ float vlds[HH * DD];
    int h = tid >> 7, d = tid & 127;
    const float* as = att_src + h * CC;
    const float* ad = att_dst + h * CC;
    const float* ae = att_edge + h * CC;
    float us = 0.f, ud = 0.f, vv = 0.f;
    for (int c = 0; c < CC; ++c) {
      float wl = W_lin[d * HC + h * CC + c];
      float we = W_le[d * HC + h * CC + c];
      us += wl * as[c]; ud += wl * ad[c]; vv += we * ae[c];
    }
    consts[h * 128 + d] = us;
    consts[256 + h * 128 + d] = ud;
    vlds[h * 128 + d] = vv;
    __syncthreads();
    if (tid < 16) {
      int hh = tid >> 3, k = tid & 7;
      float w = 0.f;
      for (int dd2 = 0; dd2 < DD; ++dd2) w += W_ep[k * DD + dd2] * vlds[hh * 128 + dd2];
      consts[512 + hh * 8 + k] = w;
    }
    if (tid < 2) {
      float ce = 0.f;
      for (int dd2 = 0; dd2 < DD; ++dd2) ce += b_ep[dd2] * vlds[tid * 128 + dd2];
      consts[528 + tid] = ce;
    }
  } else if (b <= 128) {
    int i = (b - 1) * 256 + tid;           // i = k*256 + c, exactly 32768
    int k = i >> 8, c = i & 255;
    wbT[c * DD + k] = f2bf(W_lin[i]);
  } else {
    int n = (b - 129) * 256 + tid;
    if (n < NN) cnt[n] = 0;
  }
}

// K_convert: per-wave dtype detect + normalize to int2 sd[] + dst histogram.
// The histogram atomic's return value IS the edge's within-node rank.
__global__ __launch_bounds__(256) void k_convert(const int* __restrict__ ei_raw,
                                                 int2v* __restrict__ sd,
                                                 int* __restrict__ cnt,
                                                 int* __restrict__ rank) {
  int lane = threadIdx.x & 63;
  int probe = ei_raw[2 * lane + 1];
  bool is64 = (__ballot(probe != 0) == 0ull);
  int i = blockIdx.x * 256 + threadIdx.x;   // grid is exact: EE/256 = 3125
  int s, d;
  if (is64) { s = ei_raw[2 * i]; d = ei_raw[2 * (EE + i)]; }
  else      { s = ei_raw[i];     d = ei_raw[EE + i]; }
  int2v v; v.x = s; v.y = d;
  sd[i] = v;
  rank[i] = atomicAdd(&cnt[d], 1);
}

// K_scan1: per-block 256-wide exclusive scan of cnt -> rowstart (intra-block).
__global__ __launch_bounds__(256) void k_scan1(const int* __restrict__ cnt,
                                               int* __restrict__ rowstart,
                                               int* __restrict__ bsum) {
  __shared__ int sp[256];
  int t = threadIdx.x, b = blockIdx.x;
  int n = b * 256 + t;
  int v = (n < NN) ? cnt[n] : 0;
  sp[t] = v;
  __syncthreads();
  for (int off = 1; off < 256; off <<= 1) {
    int u = (t >= off) ? sp[t - off] : 0;
    __syncthreads();
    sp[t] += u;
    __syncthreads();
  }
  if (n < NN) rowstart[n] = sp[t] - v;
  if (t == 255) bsum[b] = sp[255];
}

// K_scan23: every block redundantly scans the 196 block sums in LDS, then
// applies its own block offset.
__global__ __launch_bounds__(256) void k_scan23(int* __restrict__ rowstart,
                                                const int* __restrict__ bsum) {
  __shared__ int sp[256];
  int t = threadIdx.x, b = blockIdx.x;
  int v = (t < SCAN_B) ? bsum[t] : 0;
  sp[t] = v;
  __syncthreads();
  for (int off = 1; off < 256; off <<= 1) {
    int u = (t >= off) ? sp[t - off] : 0;
    __syncthreads();
    sp[t] += u;
    __syncthreads();
  }
  int boff = (b == 0) ? 0 : sp[b - 1];
  int n = b * 256 + t;
  if (n < NN) rowstart[n] += boff;
  if (n == NN) rowstart[NN] = EE;
}

// K2: h = x @ W_lin via MFMA 16x16x32 bf16. 64 rows x 256 cols, 4 waves.
// Epilogue restages through LDS -> coalesced 16B stores of head-interleaved hbuf.
__global__ __launch_bounds__(256) void k2_mfma(const float* __restrict__ x,
                                               const unsigned short* __restrict__ wbT,
                                               const float* __restrict__ consts,
                                               unsigned short* __restrict__ hbuf,
                                               float* __restrict__ a_src,
                                               float* __restrict__ a_dst) {
  __shared__ unsigned short xs[64 * 256];
  int tid = threadIdx.x;
  int n0 = blockIdx.x * 64;
  int r = tid >> 2, q = tid & 3;
  int n = n0 + r;
  bool valid = (n < NN);

  float xv[32];
  const float4* xp = (const float4*)(x + (size_t)n * DD + q * 32);
#pragma unroll
  for (int j = 0; j < 8; ++j) {
    float4 v = valid ? xp[j] : make_float4(0.f, 0.f, 0.f, 0.f);
    xv[j * 4 + 0] = v.x; xv[j * 4 + 1] = v.y; xv[j * 4 + 2] = v.z; xv[j * 4 + 3] = v.w;
  }
  float ps0 = 0.f, ps1 = 0.f, pd0 = 0.f, pd1 = 0.f;
#pragma unroll
  for (int j = 0; j < 32; j += 4) {
    float4 u0 = *(const float4*)(consts +   0 + q * 32 + j);
    float4 u1 = *(const float4*)(consts + 128 + q * 32 + j);
    float4 v0 = *(const float4*)(consts + 256 + q * 32 + j);
    float4 v1 = *(const float4*)(consts + 384 + q * 32 + j);
    ps0 += xv[j] * u0.x + xv[j+1] * u0.y + xv[j+2] * u0.z + xv[j+3] * u0.w;
    ps1 += xv[j] * u1.x + xv[j+1] * u1.y + xv[j+2] * u1.z + xv[j+3] * u1.w;
    pd0 += xv[j] * v0.x + xv[j+1] * v0.y + xv[j+2] * v0.z + xv[j+3] * v0.w;
    pd1 += xv[j] * v1.x + xv[j+1] * v1.y + xv[j+2] * v1.z + xv[j+3] * v1.w;
  }
#pragma unroll
  for (int off = 1; off < 4; off <<= 1) {
    ps0 += __shfl_xor(ps0, off); ps1 += __shfl_xor(ps1, off);
    pd0 += __shfl_xor(pd0, off); pd1 += __shfl_xor(pd1, off);
  }
  if (q == 0 && valid) {
    *(float2*)(a_src + n * 2) = make_float2(ps0, ps1);
    *(float2*)(a_dst + n * 2) = make_float2(pd0, pd1);
  }

#pragma unroll
  for (int ci = 0; ci < 4; ++ci) {
    union { short8v v; unsigned short u[8]; } pk;
#pragma unroll
    for (int j = 0; j < 8; ++j) pk.u[j] = f2bf(xv[ci * 8 + j]);
    unsigned byte = r * 256 + (q * 4 + ci) * 16;
    byte ^= (r & 7) << 4;
    *(short8v*)((char*)xs + byte) = pk.v;
  }

  int wave = tid >> 6, l = tid & 63;
  int wc = wave * 64;
  int lr = l & 15, lg = l >> 4;
  short8v bfr[4][4];
#pragma unroll
  for (int ct = 0; ct < 4; ++ct) {
    int col = wc + ct * 16 + lr;
#pragma unroll
    for (int kt = 0; kt < 4; ++kt)
      bfr[ct][kt] = *(const short8v*)(wbT + (size_t)col * DD + kt * 32 + lg * 8);
  }

  __syncthreads();

  float4v acc[4][4];
#pragma unroll
  for (int rt = 0; rt < 4; ++rt)
#pragma unroll
    for (int ct = 0; ct < 4; ++ct) acc[rt][ct] = (float4v){0.f, 0.f, 0.f, 0.f};

#pragma unroll
  for (int kt = 0; kt < 4; ++kt) {
    short8v afr[4];
#pragma unroll
    for (int rt = 0; rt < 4; ++rt) {
      int row = rt * 16 + lr;
      unsigned byte = row * 256 + kt * 64 + lg * 16;
      byte ^= (row & 7) << 4;
      afr[rt] = *(const short8v*)((const char*)xs + byte);
    }
#pragma unroll
    for (int rt = 0; rt < 4; ++rt)
#pragma unroll
      for (int ct = 0; ct < 4; ++ct)
        acc[rt][ct] = __builtin_amdgcn_mfma_f32_16x16x32_bf16(afr[rt], bfr[ct][kt], acc[rt][ct], 0, 0, 0);
  }

  // ---- epilogue: acc -> LDS (interleaved layout, row-swizzled) -> 16B stores ----
  __syncthreads();
#pragma unroll
  for (int rt = 0; rt < 4; ++rt) {
#pragma unroll
    for (int j = 0; j < 4; ++j) {
      int row = rt * 16 + lg * 4 + j;
#pragma unroll
      for (int ct = 0; ct < 4; ++ct) {
        int col = wc + ct * 16 + lr;
        int idx2 = ((col & 127) << 1) | (col >> 7);
        unsigned o = (unsigned)idx2 * 2;
        unsigned byte = row * 512 + (o ^ ((((unsigned)(row & 7) ^ ((o >> 7) & 3))) << 4));
        *(unsigned short*)((char*)xs + byte) = f2bf(acc[rt][ct][j]);
      }
    }
  }
  __syncthreads();
  {
    int r2 = tid >> 2, q2 = tid & 3;
    int n2 = n0 + r2;
    if (n2 < NN) {
#pragma unroll
      for (int k = 0; k < 8; ++k) {
        unsigned o = q2 * 128 + k * 16;
        unsigned byte = r2 * 512 + (o ^ ((((unsigned)(r2 & 7) ^ ((o >> 7) & 3))) << 4));
        short8v v = *(short8v*)((char*)xs + byte);
        *(short8v*)(hbuf + (size_t)n2 * HC + q2 * 64 + k * 8) = v;
      }
    }
  }
}

// K34: merged edge pass, ZERO atomics. score -> leaky -> ex=exp(score).
// payload[rowstart[d]+rank[e]] = {src*256, bf16(ex0)|bf16(ex1)<<16}. Plain store
// (NT store regressed: payload must stay L2-resident for k5's critical-path read).
__global__ __launch_bounds__(256) void k34_edge(const int2v* __restrict__ sd,
                                                const int* __restrict__ rank,
                                                const int* __restrict__ rowstart,
                                                const float* __restrict__ edge_attr,
                                                const float* __restrict__ a_src,
                                                const float* __restrict__ a_dst,
                                                const float* __restrict__ consts,
                                                int2v* __restrict__ payload) {
  int e = blockIdx.x * 256 + threadIdx.x;   // grid exact: EE/256
  int2v sdv = sd[e];
  int s = sdv.x, d = sdv.y;
  float4 ea0 = *(const float4*)(edge_attr + (size_t)e * 8);
  float4 ea1 = *(const float4*)(edge_attr + (size_t)e * 8 + 4);
  float2 asv = *(const float2*)(a_src + s * 2);
  float2 adv = *(const float2*)(a_dst + d * 2);
  const float* w0 = consts + 512;
  const float* w1 = consts + 520;
  float sc0 = asv.x + adv.x + consts[528]
            + ea0.x * w0[0] + ea0.y * w0[1] + ea0.z * w0[2] + ea0.w * w0[3]
            + ea1.x * w0[4] + ea1.y * w0[5] + ea1.z * w0[6] + ea1.w * w0[7];
  float sc1 = asv.y + adv.y + consts[529]
            + ea0.x * w1[0] + ea0.y * w1[1] + ea0.z * w1[2] + ea0.w * w1[3]
            + ea1.x * w1[4] + ea1.y * w1[5] + ea1.z * w1[6] + ea1.w * w1[7];
  sc0 = (sc0 >= 0.f) ? sc0 : LEAKY * sc0;
  sc1 = (sc1 >= 0.f) ? sc1 : LEAKY * sc1;
  float ex0 = __expf(sc0);
  float ex1 = __expf(sc1);
  unsigned pk = (unsigned)f2bf(ex0) | ((unsigned)f2bf(ex1) << 16);
  int pos = rowstart[d] + rank[e];
  int2v pv; pv.x = s << 8; pv.y = (int)pk;
  payload[pos] = pv;
}

// K5: wave per node. CSR walk, 3-deep payload / 2-deep gather pipeline.
// payload.x pre-scaled (src*256 ushorts). One ushort4 per lane per edge.
// readfirstlane forces scalar (SMEM) path for the wave-uniform payload stream.
__global__ __launch_bounds__(256) void k5_fused(const int* __restrict__ rowstart,
                                                const int2v* __restrict__ payload,
                                                const unsigned short* __restrict__ hb2,
                                                const float* __restrict__ x,
                                                const float* __restrict__ bias,
                                                const float* __restrict__ gamma,
                                                const float* __restrict__ beta,
                                                float* __restrict__ out) {
  int n = blockIdx.x * 4 + (threadIdx.x >> 6);
  int lane = threadIdx.x & 63;
  if (n >= NN) return;
  int p0 = __builtin_amdgcn_readfirstlane(rowstart[n]);
  int p1 = __builtin_amdgcn_readfirstlane(rowstart[n + 1]);
  int len = p1 - p0;
  int c0 = lane * 2;
  const int2v* pp = payload + p0;
  float a00 = 0.f, a01 = 0.f, a10 = 0.f, a11 = 0.f, se0 = 0.f, se1 = 0.f;

#define K5_LD(soff) (*(const ushort4*)(hb2 + (size_t)(unsigned)(soff) + lane * 4))
#define K5_ACC(pl, hv) { \
    float ex0 = bf2f((unsigned short)((unsigned)(pl).y & 0xffffu)); \
    float ex1 = bf2f((unsigned short)(((unsigned)(pl).y) >> 16)); \
    a00 = fmaf(ex0, bf2f((hv).x), a00); \
    a01 = fmaf(ex1, bf2f((hv).y), a01); \
    a10 = fmaf(ex0, bf2f((hv).z), a10); \
    a11 = fmaf(ex1, bf2f((hv).w), a11); \
    se0 += ex0; se1 += ex1; }

  if (len > 0) {
    int2v pl0 = pp[0];
    int2v pl1 = (len > 1) ? pp[1] : pl0;
    int2v pl2 = (len > 2) ? pp[2] : pl1;
    ushort4 h0 = K5_LD(pl0.x);
    ushort4 h1 = K5_LD(pl1.x);
    int i = 0;
    for (; i + 3 < len; ++i) {
      int2v pl3 = pp[i + 3];
      ushort4 h2 = K5_LD(pl2.x);
      K5_ACC(pl0, h0);
      pl0 = pl1; pl1 = pl2; pl2 = pl3; h0 = h1; h1 = h2;
    }
    if (i + 2 < len) {
      ushort4 h2 = K5_LD(pl2.x);
      K5_ACC(pl0, h0);
      pl0 = pl1; pl1 = pl2; h0 = h1; h1 = h2;
      ++i;
    }
    if (i + 1 < len) {
      K5_ACC(pl0, h0);
      pl0 = pl1; h0 = h1;
      ++i;
    }
    K5_ACC(pl0, h0);
  }
#undef K5_LD
#undef K5_ACC

  float inv0 = 0.5f / (se0 + SMEPS);
  float inv1 = 0.5f / (se1 + SMEPS);
  float2 xv = *(const float2*)(x + (size_t)n * DD + c0);
  float v0 = a00 * inv0 + a01 * inv1 + bias[c0] + xv.x;
  float v1 = a10 * inv0 + a11 * inv1 + bias[c0 + 1] + xv.y;
  float s = v0 + v1, ss = v0 * v0 + v1 * v1;
#pragma unroll
  for (int o = 32; o > 0; o >>= 1) {
    s += __shfl_xor(s, o);
    ss += __shfl_xor(ss, o);
  }
  float mu = s * (1.f / 128.f);
  float var = ss * (1.f / 128.f) - mu * mu;
  float rstd = rsqrtf(var + LNEPS);
  float2 ov;
  ov.x = (v0 - mu) * rstd * gamma[c0] + beta[c0];
  ov.y = (v1 - mu) * rstd * gamma[c0 + 1] + beta[c0 + 1];
  *(float2*)(out + (size_t)n * CC + c0) = ov;
}

extern "C" void kernel_launch(void* const* d_in, const int* in_sizes, int n_in,
                              void* d_out, int out_size, void* d_ws, size_t ws_size,
                              hipStream_t stream) {
  const float* x        = (const float*)d_in[0];
  const int*   ei_raw   = (const int*)d_in[1];
  const float* edge_attr= (const float*)d_in[2];
  const float* W_ep     = (const float*)d_in[3];
  const float* b_ep     = (const float*)d_in[4];
  const float* W_lin    = (const float*)d_in[5];
  const float* att_src  = (const float*)d_in[6];
  const float* att_dst  = (const float*)d_in[7];
  const float* W_le     = (const float*)d_in[8];
  const float* att_edge = (const float*)d_in[9];
  const float* bias_gat = (const float*)d_in[10];
  const float* ln_gamma = (const float*)d_in[11];
  const float* ln_beta  = (const float*)d_in[12];

  char* ws = (char*)d_ws;
  unsigned short* hbuf = (unsigned short*)(ws + HB_OFF);
  float*    a_src  = (float*)(ws + ASRC_OFF);
  float*    a_dst  = (float*)(ws + ADST_OFF);
  float*    consts = (float*)(ws + CONST_OFF);
  int2v*    sd     = (int2v*)(ws + SD_OFF);
  int*      rank   = (int*)(ws + RANK_OFF);
  int*      cnt    = (int*)(ws + CNT_OFF);
  int*      rowst  = (int*)(ws + ROW_OFF);
  int2v*    payload= (int2v*)(ws + PAY_OFF);
  unsigned short* wbT = (unsigned short*)(ws + WBT_OFF);
  int*      bsum   = (int*)(ws + BSUM_OFF);

  k01_prep<<<325, 256, 0, stream>>>(W_lin, att_src, att_dst, W_le, att_edge, W_ep, b_ep,
                                    consts, wbT, cnt);
  k_convert<<<EE / 256, 256, 0, stream>>>(ei_raw, sd, cnt, rank);
  k_scan1<<<SCAN_B, 256, 0, stream>>>(cnt, rowst, bsum);
  k_scan23<<<SCAN_B, 256, 0, stream>>>(rowst, bsum);
  k2_mfma<<<(NN + 63) / 64, 256, 0, stream>>>(x, wbT, consts, hbuf, a_src, a_dst);
  k34_edge<<<EE / 256, 256, 0, stream>>>(sd, rank, rowst, edge_attr, a_src, a_dst, consts, payload);
  k5_fused<<<(NN + 3) / 4, 256, 0, stream>>>(rowst, payload, hbuf, x, bias_gat, ln_gamma, ln_beta, (float*)d_out);
}

// Round 12
// 168.092 us; speedup vs baseline: 1.2848x; 1.1212x over previous
//
#include <hip/hip_runtime.h>
#include <hip/hip_bf16.h>

#define NN 50000
#define EE 800000
#define DD 128
#define HH 2
#define CC 128
#define HC 256
#define EDD 8

#define LEAKY 0.2f
#define SMEPS 1e-16f
#define LNEPS 1e-5f

#define SCAN_B 196   // ceil(NN/256)
#define CONV_B 3125  // EE/256
#define K2_B   782   // ceil(NN/64)

// ---- ws byte offsets ----
#define HB_OFF    0u           // bf16 h interleaved [n][c][head]: NN*HC*2 = 25,600,000
#define ASRC_OFF  25600000u    // f32 a_src: NN*2*4 = 400,000
#define ADST_OFF  26000000u    // f32 a_dst         = 400,000
#define CONST_OFF 26400000u    // 530 floats (pad 4096)
#define SD_OFF    26404096u    // int2 sd: EE*8     = 6,400,000 (rank packed in .y)
#define CNT_OFF   32804096u    // int32 cnt: 50176  = 200,704
#define ROW_OFF   33004800u    // int32 rowstart    = 200,704
#define PAY_OFF   33205504u    // int2 payload: EE*8= 6,400,000
#define WBT_OFF   39605504u    // bf16 wbT[256][128]= 65,536
#define BSUM_OFF  39671040u    // int32 bsum: 256
// total ~39.7 MB

typedef __attribute__((ext_vector_type(8))) short short8v;   // 8 bf16 (4 VGPR)
typedef __attribute__((ext_vector_type(4))) float float4v;   // MFMA acc
typedef __attribute__((ext_vector_type(2))) int int2v;

__device__ __forceinline__ float bf2f(unsigned short v) {
  return __uint_as_float(((unsigned)v) << 16);
}
__device__ __forceinline__ unsigned short f2bf(float f) {
  __hip_bfloat16 b = __float2bfloat16(f);
  return *reinterpret_cast<unsigned short*>(&b);
}

// KA: fused prep + convert.
// Block 0: attention-projection collapse -> consts. Blocks 1..128: W_lin -> bf16
// transposed wbT. Blocks 129..3253: edge_index normalize + histogram + rank
// (rank packed into sd.y upper bits; d fits in 16 bits since NN<65536).
__global__ __launch_bounds__(256) void kA_prep_convert(const float* __restrict__ W_lin,
                                                       const float* __restrict__ att_src,
                                                       const float* __restrict__ att_dst,
                                                       const float* __restrict__ W_le,
                                                       const float* __restrict__ att_edge,
                                                       const float* __restrict__ W_ep,
                                                       const float* __restrict__ b_ep,
                                                       const int* __restrict__ ei_raw,
                                                       float* __restrict__ consts,
                                                       unsigned short* __restrict__ wbT,
                                                       int* __restrict__ cnt,
                                                       int2v* __restrict__ sd) {
  int b = blockIdx.x, tid = threadIdx.x;
  if (b == 0) {
    __shared__ float vlds[HH * DD];
    int h = tid >> 7, d = tid & 127;
    const float* as = att_src + h * CC;
    const float* ad = att_dst + h * CC;
    const float* ae = att_edge + h * CC;
    float us = 0.f, ud = 0.f, vv = 0.f;
    for (int c = 0; c < CC; ++c) {
      float wl = W_lin[d * HC + h * CC + c];
      float we = W_le[d * HC + h * CC + c];
      us += wl * as[c]; ud += wl * ad[c]; vv += we * ae[c];
    }
    consts[h * 128 + d] = us;
    consts[256 + h * 128 + d] = ud;
    vlds[h * 128 + d] = vv;
    __syncthreads();
    if (tid < 16) {
      int hh = tid >> 3, k = tid & 7;
      float w = 0.f;
      for (int dd2 = 0; dd2 < DD; ++dd2) w += W_ep[k * DD + dd2] * vlds[hh * 128 + dd2];
      consts[512 + hh * 8 + k] = w;
    }
    if (tid < 2) {
      float ce = 0.f;
      for (int dd2 = 0; dd2 < DD; ++dd2) ce += b_ep[dd2] * vlds[tid * 128 + dd2];
      consts[528 + tid] = ce;
    }
  } else if (b <= 128) {
    int i = (b - 1) * 256 + tid;           // i = k*256 + c, exactly 32768
    int k = i >> 8, c = i & 255;
    wbT[c * DD + k] = f2bf(W_lin[i]);
  } else {
    // wave-uniform dtype detect: int64 iff 64 probe odd-words all zero
    int lane = threadIdx.x & 63;
    int probe = ei_raw[2 * lane + 1];
    bool is64 = (__ballot(probe != 0) == 0ull);
    int i = (b - 129) * 256 + tid;         // exact: CONV_B*256 = EE
    int s, d;
    if (is64) { s = ei_raw[2 * i]; d = ei_raw[2 * (EE + i)]; }
    else      { s = ei_raw[i];     d = ei_raw[EE + i]; }
    int rk = atomicAdd(&cnt[d], 1);
    int2v v; v.x = s; v.y = d | (rk << 16);
    sd[i] = v;
  }
}

// K_scan1: per-block 256-wide exclusive scan of cnt -> rowstart (intra-block).
__global__ __launch_bounds__(256) void k_scan1(const int* __restrict__ cnt,
                                               int* __restrict__ rowstart,
                                               int* __restrict__ bsum) {
  __shared__ int sp[256];
  int t = threadIdx.x, b = blockIdx.x;
  int n = b * 256 + t;
  int v = (n < NN) ? cnt[n] : 0;
  sp[t] = v;
  __syncthreads();
  for (int off = 1; off < 256; off <<= 1) {
    int u = (t >= off) ? sp[t - off] : 0;
    __syncthreads();
    sp[t] += u;
    __syncthreads();
  }
  if (n < NN) rowstart[n] = sp[t] - v;
  if (t == 255) bsum[b] = sp[255];
}

// KB: fused scan23 + k2_mfma. Blocks 0..195: finish the prefix scan (every block
// redundantly scans the 196 block sums in LDS, applies own offset). Blocks
// 196..977: MFMA node projection (64 rows x 256 cols, 4 waves), fused a_src/a_dst,
// LDS-restaged coalesced epilogue into head-interleaved hbuf.
__global__ __launch_bounds__(256) void kB_scan_mfma(int* __restrict__ rowstart,
                                                    const int* __restrict__ bsum,
                                                    const float* __restrict__ x,
                                                    const unsigned short* __restrict__ wbT,
                                                    const float* __restrict__ consts,
                                                    unsigned short* __restrict__ hbuf,
                                                    float* __restrict__ a_src,
                                                    float* __restrict__ a_dst) {
  __shared__ unsigned short xs[64 * 256];   // 32KB (scan part uses first 1KB)
  int tid = threadIdx.x;

  if (blockIdx.x < SCAN_B) {
    int* sp = (int*)xs;
    int t = tid, b = blockIdx.x;
    int v = (t < SCAN_B) ? bsum[t] : 0;
    sp[t] = v;
    __syncthreads();
    for (int off = 1; off < 256; off <<= 1) {
      int u = (t >= off) ? sp[t - off] : 0;
      __syncthreads();
      sp[t] += u;
      __syncthreads();
    }
    int boff = (b == 0) ? 0 : sp[b - 1];
    int n = b * 256 + t;
    if (n < NN) rowstart[n] += boff;
    if (n == NN) rowstart[NN] = EE;   // b=195, t=80
    return;
  }

  int n0 = (blockIdx.x - SCAN_B) * 64;
  int r = tid >> 2, q = tid & 3;
  int n = n0 + r;
  bool valid = (n < NN);

  float xv[32];
  const float4* xp = (const float4*)(x + (size_t)n * DD + q * 32);
#pragma unroll
  for (int j = 0; j < 8; ++j) {
    float4 v = valid ? xp[j] : make_float4(0.f, 0.f, 0.f, 0.f);
    xv[j * 4 + 0] = v.x; xv[j * 4 + 1] = v.y; xv[j * 4 + 2] = v.z; xv[j * 4 + 3] = v.w;
  }
  float ps0 = 0.f, ps1 = 0.f, pd0 = 0.f, pd1 = 0.f;
#pragma unroll
  for (int j = 0; j < 32; j += 4) {
    float4 u0 = *(const float4*)(consts +   0 + q * 32 + j);
    float4 u1 = *(const float4*)(consts + 128 + q * 32 + j);
    float4 v0 = *(const float4*)(consts + 256 + q * 32 + j);
    float4 v1 = *(const float4*)(consts + 384 + q * 32 + j);
    ps0 += xv[j] * u0.x + xv[j+1] * u0.y + xv[j+2] * u0.z + xv[j+3] * u0.w;
    ps1 += xv[j] * u1.x + xv[j+1] * u1.y + xv[j+2] * u1.z + xv[j+3] * u1.w;
    pd0 += xv[j] * v0.x + xv[j+1] * v0.y + xv[j+2] * v0.z + xv[j+3] * v0.w;
    pd1 += xv[j] * v1.x + xv[j+1] * v1.y + xv[j+2] * v1.z + xv[j+3] * v1.w;
  }
#pragma unroll
  for (int off = 1; off < 4; off <<= 1) {
    ps0 += __shfl_xor(ps0, off); ps1 += __shfl_xor(ps1, off);
    pd0 += __shfl_xor(pd0, off); pd1 += __shfl_xor(pd1, off);
  }
  if (q == 0 && valid) {
    *(float2*)(a_src + n * 2) = make_float2(ps0, ps1);
    *(float2*)(a_dst + n * 2) = make_float2(pd0, pd1);
  }

#pragma unroll
  for (int ci = 0; ci < 4; ++ci) {
    union { short8v v; unsigned short u[8]; } pk;
#pragma unroll
    for (int j = 0; j < 8; ++j) pk.u[j] = f2bf(xv[ci * 8 + j]);
    unsigned byte = r * 256 + (q * 4 + ci) * 16;
    byte ^= (r & 7) << 4;
    *(short8v*)((char*)xs + byte) = pk.v;
  }

  int wave = tid >> 6, l = tid & 63;
  int wc = wave * 64;
  int lr = l & 15, lg = l >> 4;
  short8v bfr[4][4];
#pragma unroll
  for (int ct = 0; ct < 4; ++ct) {
    int col = wc + ct * 16 + lr;
#pragma unroll
    for (int kt = 0; kt < 4; ++kt)
      bfr[ct][kt] = *(const short8v*)(wbT + (size_t)col * DD + kt * 32 + lg * 8);
  }

  __syncthreads();

  float4v acc[4][4];
#pragma unroll
  for (int rt = 0; rt < 4; ++rt)
#pragma unroll
    for (int ct = 0; ct < 4; ++ct) acc[rt][ct] = (float4v){0.f, 0.f, 0.f, 0.f};

#pragma unroll
  for (int kt = 0; kt < 4; ++kt) {
    short8v afr[4];
#pragma unroll
    for (int rt = 0; rt < 4; ++rt) {
      int row = rt * 16 + lr;
      unsigned byte = row * 256 + kt * 64 + lg * 16;
      byte ^= (row & 7) << 4;
      afr[rt] = *(const short8v*)((const char*)xs + byte);
    }
#pragma unroll
    for (int rt = 0; rt < 4; ++rt)
#pragma unroll
      for (int ct = 0; ct < 4; ++ct)
        acc[rt][ct] = __builtin_amdgcn_mfma_f32_16x16x32_bf16(afr[rt], bfr[ct][kt], acc[rt][ct], 0, 0, 0);
  }

  // epilogue: acc -> LDS (interleaved layout, row-swizzled) -> coalesced 16B stores
  __syncthreads();
#pragma unroll
  for (int rt = 0; rt < 4; ++rt) {
#pragma unroll
    for (int j = 0; j < 4; ++j) {
      int row = rt * 16 + lg * 4 + j;
#pragma unroll
      for (int ct = 0; ct < 4; ++ct) {
        int col = wc + ct * 16 + lr;
        int idx2 = ((col & 127) << 1) | (col >> 7);
        unsigned o = (unsigned)idx2 * 2;
        unsigned byte = row * 512 + (o ^ ((((unsigned)(row & 7) ^ ((o >> 7) & 3))) << 4));
        *(unsigned short*)((char*)xs + byte) = f2bf(acc[rt][ct][j]);
      }
    }
  }
  __syncthreads();
  {
    int r2 = tid >> 2, q2 = tid & 3;
    int n2 = n0 + r2;
    if (n2 < NN) {
#pragma unroll
      for (int k = 0; k < 8; ++k) {
        unsigned o = q2 * 128 + k * 16;
        unsigned byte = r2 * 512 + (o ^ ((((unsigned)(r2 & 7) ^ ((o >> 7) & 3))) << 4));
        short8v v = *(short8v*)((char*)xs + byte);
        *(short8v*)(hbuf + (size_t)n2 * HC + q2 * 64 + k * 8) = v;
      }
    }
  }
}

// K34: edge pass, ZERO atomics. score -> leaky -> ex=exp(score) (shift-invariant
// softmax; scores bounded ~|9|). payload[rowstart[d]+rank] = {src*256, bf16 ex pair}.
__global__ __launch_bounds__(256) void k34_edge(const int2v* __restrict__ sd,
                                                const int* __restrict__ rowstart,
                                                const float* __restrict__ edge_attr,
                                                const float* __restrict__ a_src,
                                                const float* __restrict__ a_dst,
                                                const float* __restrict__ consts,
                                                int2v* __restrict__ payload) {
  int e = blockIdx.x * 256 + threadIdx.x;   // grid exact: EE/256
  int2v sdv = sd[e];
  int s = sdv.x;
  unsigned y = (unsigned)sdv.y;
  int d = (int)(y & 0xFFFFu);
  int rk = (int)(y >> 16);
  float4 ea0 = *(const float4*)(edge_attr + (size_t)e * 8);
  float4 ea1 = *(const float4*)(edge_attr + (size_t)e * 8 + 4);
  float2 asv = *(const float2*)(a_src + s * 2);
  float2 adv = *(const float2*)(a_dst + d * 2);
  const float* w0 = consts + 512;
  const float* w1 = consts + 520;
  float sc0 = asv.x + adv.x + consts[528]
            + ea0.x * w0[0] + ea0.y * w0[1] + ea0.z * w0[2] + ea0.w * w0[3]
            + ea1.x * w0[4] + ea1.y * w0[5] + ea1.z * w0[6] + ea1.w * w0[7];
  float sc1 = asv.y + adv.y + consts[529]
            + ea0.x * w1[0] + ea0.y * w1[1] + ea0.z * w1[2] + ea0.w * w1[3]
            + ea1.x * w1[4] + ea1.y * w1[5] + ea1.z * w1[6] + ea1.w * w1[7];
  sc0 = (sc0 >= 0.f) ? sc0 : LEAKY * sc0;
  sc1 = (sc1 >= 0.f) ? sc1 : LEAKY * sc1;
  float ex0 = __expf(sc0);
  float ex1 = __expf(sc1);
  unsigned pk = (unsigned)f2bf(ex0) | ((unsigned)f2bf(ex1) << 16);
  int pos = rowstart[d] + rk;
  int2v pv; pv.x = s << 8; pv.y = (int)pk;
  payload[pos] = pv;
}

// K5: wave per node. CSR walk, depth-4 batched pipeline: next batch's 4 scalar
// payload loads + 4 h-gathers issue BEFORE current batch's FMAs consume.
__global__ __launch_bounds__(256) void k5_fused(const int* __restrict__ rowstart,
                                                const int2v* __restrict__ payload,
                                                const unsigned short* __restrict__ hb2,
                                                const float* __restrict__ x,
                                                const float* __restrict__ bias,
                                                const float* __restrict__ gamma,
                                                const float* __restrict__ beta,
                                                float* __restrict__ out) {
  int n = blockIdx.x * 4 + (threadIdx.x >> 6);
  int lane = threadIdx.x & 63;
  if (n >= NN) return;
  int p0i = __builtin_amdgcn_readfirstlane(rowstart[n]);
  int p1i = __builtin_amdgcn_readfirstlane(rowstart[n + 1]);
  int len = p1i - p0i;
  int c0 = lane * 2;
  const int2v* pp = payload + p0i;
  float a00 = 0.f, a01 = 0.f, a10 = 0.f, a11 = 0.f, se0 = 0.f, se1 = 0.f;

#define K5_LD(soff) (*(const ushort4*)(hb2 + (size_t)(unsigned)(soff) + lane * 4))
#define K5_ACC(pl, hv) { \
    float ex0 = bf2f((unsigned short)((unsigned)(pl).y & 0xffffu)); \
    float ex1 = bf2f((unsigned short)(((unsigned)(pl).y) >> 16)); \
    a00 = fmaf(ex0, bf2f((hv).x), a00); \
    a01 = fmaf(ex1, bf2f((hv).y), a01); \
    a10 = fmaf(ex0, bf2f((hv).z), a10); \
    a11 = fmaf(ex1, bf2f((hv).w), a11); \
    se0 += ex0; se1 += ex1; }

  if (len > 0) {
    int2v p0 = pp[0];
    int2v p1 = (len > 1) ? pp[1] : p0;
    int2v p2 = (len > 2) ? pp[2] : p0;
    int2v p3 = (len > 3) ? pp[3] : p0;
    ushort4 h0 = K5_LD(p0.x), h1 = K5_LD(p1.x), h2 = K5_LD(p2.x), h3 = K5_LD(p3.x);
    int i = 0;
    for (; i + 7 < len; i += 4) {
      int2v q0 = pp[i + 4], q1 = pp[i + 5], q2 = pp[i + 6], q3 = pp[i + 7];
      ushort4 g0 = K5_LD(q0.x), g1 = K5_LD(q1.x), g2 = K5_LD(q2.x), g3 = K5_LD(q3.x);
      K5_ACC(p0, h0); K5_ACC(p1, h1); K5_ACC(p2, h2); K5_ACC(p3, h3);
      p0 = q0; p1 = q1; p2 = q2; p3 = q3;
      h0 = g0; h1 = g1; h2 = g2; h3 = g3;
    }
    int r = len - i;           // 1..7
    K5_ACC(p0, h0);
    if (r > 1) K5_ACC(p1, h1);
    if (r > 2) K5_ACC(p2, h2);
    if (r > 3) K5_ACC(p3, h3);
    if (r > 4) {
      int rem = r - 4;         // 1..3
      int2v q0 = pp[i + 4];
      int2v q1 = (rem > 1) ? pp[i + 5] : q0;
      int2v q2 = (rem > 2) ? pp[i + 6] : q0;
      ushort4 g0 = K5_LD(q0.x), g1 = K5_LD(q1.x), g2 = K5_LD(q2.x);
      K5_ACC(q0, g0);
      if (rem > 1) K5_ACC(q1, g1);
      if (rem > 2) K5_ACC(q2, g2);
    }
  }
#undef K5_LD
#undef K5_ACC

  float inv0 = 0.5f / (se0 + SMEPS);
  float inv1 = 0.5f / (se1 + SMEPS);
  float2 xv = *(const float2*)(x + (size_t)n * DD + c0);
  float v0 = a00 * inv0 + a01 * inv1 + bias[c0] + xv.x;
  float v1 = a10 * inv0 + a11 * inv1 + bias[c0 + 1] + xv.y;
  float s = v0 + v1, ss = v0 * v0 + v1 * v1;
#pragma unroll
  for (int o = 32; o > 0; o >>= 1) {
    s += __shfl_xor(s, o);
    ss += __shfl_xor(ss, o);
  }
  float mu = s * (1.f / 128.f);
  float var = ss * (1.f / 128.f) - mu * mu;
  float rstd = rsqrtf(var + LNEPS);
  float2 ov;
  ov.x = (v0 - mu) * rstd * gamma[c0] + beta[c0];
  ov.y = (v1 - mu) * rstd * gamma[c0 + 1] + beta[c0 + 1];
  *(float2*)(out + (size_t)n * CC + c0) = ov;
}

extern "C" void kernel_launch(void* const* d_in, const int* in_sizes, int n_in,
                              void* d_out, int out_size, void* d_ws, size_t ws_size,
                              hipStream_t stream) {
  const float* x        = (const float*)d_in[0];
  const int*   ei_raw   = (const int*)d_in[1];
  const float* edge_attr= (const float*)d_in[2];
  const float* W_ep     = (const float*)d_in[3];
  const float* b_ep     = (const float*)d_in[4];
  const float* W_lin    = (const float*)d_in[5];
  const float* att_src  = (const float*)d_in[6];
  const float* att_dst  = (const float*)d_in[7];
  const float* W_le     = (const float*)d_in[8];
  const float* att_edge = (const float*)d_in[9];
  const float* bias_gat = (const float*)d_in[10];
  const float* ln_gamma = (const float*)d_in[11];
  const float* ln_beta  = (const float*)d_in[12];

  char* ws = (char*)d_ws;
  unsigned short* hbuf = (unsigned short*)(ws + HB_OFF);
  float*    a_src  = (float*)(ws + ASRC_OFF);
  float*    a_dst  = (float*)(ws + ADST_OFF);
  float*    consts = (float*)(ws + CONST_OFF);
  int2v*    sd     = (int2v*)(ws + SD_OFF);
  int*      cnt    = (int*)(ws + CNT_OFF);
  int*      rowst  = (int*)(ws + ROW_OFF);
  int2v*    payload= (int2v*)(ws + PAY_OFF);
  unsigned short* wbT = (unsigned short*)(ws + WBT_OFF);
  int*      bsum   = (int*)(ws + BSUM_OFF);

  hipMemsetAsync(cnt, 0, (size_t)NN * 4, stream);
  kA_prep_convert<<<129 + CONV_B, 256, 0, stream>>>(W_lin, att_src, att_dst, W_le, att_edge,
                                                    W_ep, b_ep, ei_raw, consts, wbT, cnt, sd);
  k_scan1<<<SCAN_B, 256, 0, stream>>>(cnt, rowst, bsum);
  kB_scan_mfma<<<SCAN_B + K2_B, 256, 0, stream>>>(rowst, bsum, x, wbT, consts, hbuf, a_src, a_dst);
  k34_edge<<<CONV_B, 256, 0, stream>>>(sd, rowst, edge_attr, a_src, a_dst, consts, payload);
  k5_fused<<<(NN + 3) / 4, 256, 0, stream>>>(rowst, payload, hbuf, x, bias_gat, ln_gamma, ln_beta, (float*)d_out);
}

// Round 13
// 145.938 us; speedup vs baseline: 1.4798x; 1.1518x over previous
//
#include <hip/hip_runtime.h>
#include <hip/hip_bf16.h>

#define NN 50000
#define EE 800000
#define DD 128
#define HH 2
#define CC 128
#define HC 256
#define EDD 8

#define LEAKY 0.2f
#define SMEPS 1e-16f
#define LNEPS 1e-5f

#define SCAN_B 196   // ceil(NN/256)
#define CONV_B 3125  // EE/256
#define K2_B   782   // ceil(NN/64)

// ---- ws byte offsets ----
#define HB_OFF    0u           // fp8 h interleaved [n][c][head]: NN*256B = 12,800,000
#define ASRC_OFF  25600000u    // f32 a_src: NN*2*4 = 400,000
#define ADST_OFF  26000000u    // f32 a_dst         = 400,000
#define CONST_OFF 26400000u    // 530 floats (pad 4096)
#define SD_OFF    26404096u    // int2 sd: EE*8     = 6,400,000 (rank packed in .y)
#define CNT_OFF   32804096u    // int32 cnt: 50176  = 200,704
#define ROW_OFF   33004800u    // int32 rowstart    = 200,704
#define PAY_OFF   33205504u    // int2 payload: EE*8= 6,400,000
#define WBT_OFF   39605504u    // bf16 wbT[256][128]= 65,536
#define BSUM_OFF  39671040u    // int32 bsum: 256

typedef __attribute__((ext_vector_type(8))) short short8v;   // 8 bf16 (4 VGPR)
typedef __attribute__((ext_vector_type(4))) float float4v;   // MFMA acc
typedef __attribute__((ext_vector_type(2))) int int2v;

__device__ __forceinline__ float bf2f(unsigned short v) {
  return __uint_as_float(((unsigned)v) << 16);
}
__device__ __forceinline__ unsigned short f2bf(float f) {
  __hip_bfloat16 b = __float2bfloat16(f);
  return *reinterpret_cast<unsigned short*>(&b);
}

// KA: fused prep + convert.
// Block 0: attention-projection collapse -> consts. Blocks 1..128: W_lin -> bf16
// transposed wbT. Blocks 129..3253: edge_index normalize + histogram + rank
// (rank packed into sd.y upper bits; d fits in 16 bits since NN<65536).
__global__ __launch_bounds__(256) void kA_prep_convert(const float* __restrict__ W_lin,
                                                       const float* __restrict__ att_src,
                                                       const float* __restrict__ att_dst,
                                                       const float* __restrict__ W_le,
                                                       const float* __restrict__ att_edge,
                                                       const float* __restrict__ W_ep,
                                                       const float* __restrict__ b_ep,
                                                       const int* __restrict__ ei_raw,
                                                       float* __restrict__ consts,
                                                       unsigned short* __restrict__ wbT,
                                                       int* __restrict__ cnt,
                                                       int2v* __restrict__ sd) {
  int b = blockIdx.x, tid = threadIdx.x;
  if (b == 0) {
    __shared__ float vlds[HH * DD];
    int h = tid >> 7, d = tid & 127;
    const float* as = att_src + h * CC;
    const float* ad = att_dst + h * CC;
    const float* ae = att_edge + h * CC;
    float us = 0.f, ud = 0.f, vv = 0.f;
    for (int c = 0; c < CC; ++c) {
      float wl = W_lin[d * HC + h * CC + c];
      float we = W_le[d * HC + h * CC + c];
      us += wl * as[c]; ud += wl * ad[c]; vv += we * ae[c];
    }
    consts[h * 128 + d] = us;
    consts[256 + h * 128 + d] = ud;
    vlds[h * 128 + d] = vv;
    __syncthreads();
    if (tid < 16) {
      int hh = tid >> 3, k = tid & 7;
      float w = 0.f;
      for (int dd2 = 0; dd2 < DD; ++dd2) w += W_ep[k * DD + dd2] * vlds[hh * 128 + dd2];
      consts[512 + hh * 8 + k] = w;
    }
    if (tid < 2) {
      float ce = 0.f;
      for (int dd2 = 0; dd2 < DD; ++dd2) ce += b_ep[dd2] * vlds[tid * 128 + dd2];
      consts[528 + tid] = ce;
    }
  } else if (b <= 128) {
    int i = (b - 1) * 256 + tid;           // i = k*256 + c, exactly 32768
    int k = i >> 8, c = i & 255;
    wbT[c * DD + k] = f2bf(W_lin[i]);
  } else {
    int lane = threadIdx.x & 63;
    int probe = ei_raw[2 * lane + 1];
    bool is64 = (__ballot(probe != 0) == 0ull);
    int i = (b - 129) * 256 + tid;         // exact: CONV_B*256 = EE
    int s, d;
    if (is64) { s = ei_raw[2 * i]; d = ei_raw[2 * (EE + i)]; }
    else      { s = ei_raw[i];     d = ei_raw[EE + i]; }
    int rk = atomicAdd(&cnt[d], 1);
    int2v v; v.x = s; v.y = d | (rk << 16);
    sd[i] = v;
  }
}

// K_scan1: per-block 256-wide exclusive scan of cnt -> rowstart (intra-block).
__global__ __launch_bounds__(256) void k_scan1(const int* __restrict__ cnt,
                                               int* __restrict__ rowstart,
                                               int* __restrict__ bsum) {
  __shared__ int sp[256];
  int t = threadIdx.x, b = blockIdx.x;
  int n = b * 256 + t;
  int v = (n < NN) ? cnt[n] : 0;
  sp[t] = v;
  __syncthreads();
  for (int off = 1; off < 256; off <<= 1) {
    int u = (t >= off) ? sp[t - off] : 0;
    __syncthreads();
    sp[t] += u;
    __syncthreads();
  }
  if (n < NN) rowstart[n] = sp[t] - v;
  if (t == 255) bsum[b] = sp[255];
}

// KB: fused scan23 + MFMA node projection. Blocks 0..195: finish prefix scan.
// Blocks 196..977: h = x @ W_lin (MFMA bf16), fused a_src/a_dst, epilogue
// converts to fp8 e4m3 and stores coalesced head-interleaved rows (256 B/node).
__global__ __launch_bounds__(256) void kB_scan_mfma(int* __restrict__ rowstart,
                                                    const int* __restrict__ bsum,
                                                    const float* __restrict__ x,
                                                    const unsigned short* __restrict__ wbT,
                                                    const float* __restrict__ consts,
                                                    unsigned char* __restrict__ hbuf8,
                                                    float* __restrict__ a_src,
                                                    float* __restrict__ a_dst) {
  __shared__ unsigned short xs[64 * 256];   // 32KB (scan part uses first 1KB)
  int tid = threadIdx.x;

  if (blockIdx.x < SCAN_B) {
    int* sp = (int*)xs;
    int t = tid, b = blockIdx.x;
    int v = (t < SCAN_B) ? bsum[t] : 0;
    sp[t] = v;
    __syncthreads();
    for (int off = 1; off < 256; off <<= 1) {
      int u = (t >= off) ? sp[t - off] : 0;
      __syncthreads();
      sp[t] += u;
      __syncthreads();
    }
    int boff = (b == 0) ? 0 : sp[b - 1];
    int n = b * 256 + t;
    if (n < NN) rowstart[n] += boff;
    if (n == NN) rowstart[NN] = EE;
    return;
  }

  int n0 = (blockIdx.x - SCAN_B) * 64;
  int r = tid >> 2, q = tid & 3;
  int n = n0 + r;
  bool valid = (n < NN);

  float xv[32];
  const float4* xp = (const float4*)(x + (size_t)n * DD + q * 32);
#pragma unroll
  for (int j = 0; j < 8; ++j) {
    float4 v = valid ? xp[j] : make_float4(0.f, 0.f, 0.f, 0.f);
    xv[j * 4 + 0] = v.x; xv[j * 4 + 1] = v.y; xv[j * 4 + 2] = v.z; xv[j * 4 + 3] = v.w;
  }
  float ps0 = 0.f, ps1 = 0.f, pd0 = 0.f, pd1 = 0.f;
#pragma unroll
  for (int j = 0; j < 32; j += 4) {
    float4 u0 = *(const float4*)(consts +   0 + q * 32 + j);
    float4 u1 = *(const float4*)(consts + 128 + q * 32 + j);
    float4 v0 = *(const float4*)(consts + 256 + q * 32 + j);
    float4 v1 = *(const float4*)(consts + 384 + q * 32 + j);
    ps0 += xv[j] * u0.x + xv[j+1] * u0.y + xv[j+2] * u0.z + xv[j+3] * u0.w;
    ps1 += xv[j] * u1.x + xv[j+1] * u1.y + xv[j+2] * u1.z + xv[j+3] * u1.w;
    pd0 += xv[j] * v0.x + xv[j+1] * v0.y + xv[j+2] * v0.z + xv[j+3] * v0.w;
    pd1 += xv[j] * v1.x + xv[j+1] * v1.y + xv[j+2] * v1.z + xv[j+3] * v1.w;
  }
#pragma unroll
  for (int off = 1; off < 4; off <<= 1) {
    ps0 += __shfl_xor(ps0, off); ps1 += __shfl_xor(ps1, off);
    pd0 += __shfl_xor(pd0, off); pd1 += __shfl_xor(pd1, off);
  }
  if (q == 0 && valid) {
    *(float2*)(a_src + n * 2) = make_float2(ps0, ps1);
    *(float2*)(a_dst + n * 2) = make_float2(pd0, pd1);
  }

#pragma unroll
  for (int ci = 0; ci < 4; ++ci) {
    union { short8v v; unsigned short u[8]; } pk;
#pragma unroll
    for (int j = 0; j < 8; ++j) pk.u[j] = f2bf(xv[ci * 8 + j]);
    unsigned byte = r * 256 + (q * 4 + ci) * 16;
    byte ^= (r & 7) << 4;
    *(short8v*)((char*)xs + byte) = pk.v;
  }

  int wave = tid >> 6, l = tid & 63;
  int wc = wave * 64;
  int lr = l & 15, lg = l >> 4;
  short8v bfr[4][4];
#pragma unroll
  for (int ct = 0; ct < 4; ++ct) {
    int col = wc + ct * 16 + lr;
#pragma unroll
    for (int kt = 0; kt < 4; ++kt)
      bfr[ct][kt] = *(const short8v*)(wbT + (size_t)col * DD + kt * 32 + lg * 8);
  }

  __syncthreads();

  float4v acc[4][4];
#pragma unroll
  for (int rt = 0; rt < 4; ++rt)
#pragma unroll
    for (int ct = 0; ct < 4; ++ct) acc[rt][ct] = (float4v){0.f, 0.f, 0.f, 0.f};

#pragma unroll
  for (int kt = 0; kt < 4; ++kt) {
    short8v afr[4];
#pragma unroll
    for (int rt = 0; rt < 4; ++rt) {
      int row = rt * 16 + lr;
      unsigned byte = row * 256 + kt * 64 + lg * 16;
      byte ^= (row & 7) << 4;
      afr[rt] = *(const short8v*)((const char*)xs + byte);
    }
#pragma unroll
    for (int rt = 0; rt < 4; ++rt)
#pragma unroll
      for (int ct = 0; ct < 4; ++ct)
        acc[rt][ct] = __builtin_amdgcn_mfma_f32_16x16x32_bf16(afr[rt], bfr[ct][kt], acc[rt][ct], 0, 0, 0);
  }

  // epilogue: acc -> LDS bf16 (interleaved, row-swizzled) -> fp8 pack -> 16B stores
  __syncthreads();
#pragma unroll
  for (int rt = 0; rt < 4; ++rt) {
#pragma unroll
    for (int j = 0; j < 4; ++j) {
      int row = rt * 16 + lg * 4 + j;
#pragma unroll
      for (int ct = 0; ct < 4; ++ct) {
        int col = wc + ct * 16 + lr;
        int idx2 = ((col & 127) << 1) | (col >> 7);
        unsigned o = (unsigned)idx2 * 2;
        unsigned byte = row * 512 + (o ^ ((((unsigned)(row & 7) ^ ((o >> 7) & 3))) << 4));
        *(unsigned short*)((char*)xs + byte) = f2bf(acc[rt][ct][j]);
      }
    }
  }
  __syncthreads();
  {
    int r2 = tid >> 2, q2 = tid & 3;
    int n2 = n0 + r2;
    if (n2 < NN) {
#pragma unroll
      for (int kk = 0; kk < 4; ++kk) {
        unsigned u4[4];
#pragma unroll
        for (int t2 = 0; t2 < 2; ++t2) {
          int k = kk * 2 + t2;
          unsigned o = q2 * 128 + k * 16;
          unsigned byte = r2 * 512 + (o ^ ((((unsigned)(r2 & 7) ^ ((o >> 7) & 3))) << 4));
          short8v v = *(short8v*)((char*)xs + byte);
          unsigned ua = __builtin_amdgcn_cvt_pk_fp8_f32(bf2f((unsigned short)v[0]), bf2f((unsigned short)v[1]), 0u, false);
          ua = __builtin_amdgcn_cvt_pk_fp8_f32(bf2f((unsigned short)v[2]), bf2f((unsigned short)v[3]), ua, true);
          unsigned ub = __builtin_amdgcn_cvt_pk_fp8_f32(bf2f((unsigned short)v[4]), bf2f((unsigned short)v[5]), 0u, false);
          ub = __builtin_amdgcn_cvt_pk_fp8_f32(bf2f((unsigned short)v[6]), bf2f((unsigned short)v[7]), ub, true);
          u4[t2 * 2] = ua; u4[t2 * 2 + 1] = ub;
        }
        uint4 w4 = make_uint4(u4[0], u4[1], u4[2], u4[3]);
        *(uint4*)(hbuf8 + (size_t)n2 * 256 + q2 * 64 + kk * 16) = w4;
      }
    }
  }
}

// K34: edge pass, ZERO atomics. score -> leaky -> ex=exp(score) (shift-invariant
// softmax; scores bounded ~|9|). payload[rowstart[d]+rank] = {src*256, bf16 ex pair}.
__global__ __launch_bounds__(256) void k34_edge(const int2v* __restrict__ sd,
                                                const int* __restrict__ rowstart,
                                                const float* __restrict__ edge_attr,
                                                const float* __restrict__ a_src,
                                                const float* __restrict__ a_dst,
                                                const float* __restrict__ consts,
                                                int2v* __restrict__ payload) {
  int e = blockIdx.x * 256 + threadIdx.x;   // grid exact: EE/256
  int2v sdv = sd[e];
  int s = sdv.x;
  unsigned y = (unsigned)sdv.y;
  int d = (int)(y & 0xFFFFu);
  int rk = (int)(y >> 16);
  float4 ea0 = *(const float4*)(edge_attr + (size_t)e * 8);
  float4 ea1 = *(const float4*)(edge_attr + (size_t)e * 8 + 4);
  float2 asv = *(const float2*)(a_src + s * 2);
  float2 adv = *(const float2*)(a_dst + d * 2);
  const float* w0 = consts + 512;
  const float* w1 = consts + 520;
  float sc0 = asv.x + adv.x + consts[528]
            + ea0.x * w0[0] + ea0.y * w0[1] + ea0.z * w0[2] + ea0.w * w0[3]
            + ea1.x * w0[4] + ea1.y * w0[5] + ea1.z * w0[6] + ea1.w * w0[7];
  float sc1 = asv.y + adv.y + consts[529]
            + ea0.x * w1[0] + ea0.y * w1[1] + ea0.z * w1[2] + ea0.w * w1[3]
            + ea1.x * w1[4] + ea1.y * w1[5] + ea1.z * w1[6] + ea1.w * w1[7];
  sc0 = (sc0 >= 0.f) ? sc0 : LEAKY * sc0;
  sc1 = (sc1 >= 0.f) ? sc1 : LEAKY * sc1;
  float ex0 = __expf(sc0);
  float ex1 = __expf(sc1);
  unsigned pk = (unsigned)f2bf(ex0) | ((unsigned)f2bf(ex1) << 16);
  int pos = rowstart[d] + rk;
  int2v pv; pv.x = s << 8; pv.y = (int)pk;   // s<<8 = byte offset of fp8 row
  payload[pos] = pv;
}

// K5: wave per node. CSR walk, depth-4 batched pipeline. Per edge each lane
// reads ONE uint (4 fp8: h0[c],h1[c],h0[c+1],h1[c+1]); HW v_cvt_f32_fp8 decode.
__global__ __launch_bounds__(256) void k5_fused(const int* __restrict__ rowstart,
                                                const int2v* __restrict__ payload,
                                                const unsigned char* __restrict__ hb8,
                                                const float* __restrict__ x,
                                                const float* __restrict__ bias,
                                                const float* __restrict__ gamma,
                                                const float* __restrict__ beta,
                                                float* __restrict__ out) {
  int n = blockIdx.x * 4 + (threadIdx.x >> 6);
  int lane = threadIdx.x & 63;
  if (n >= NN) return;
  int p0i = __builtin_amdgcn_readfirstlane(rowstart[n]);
  int p1i = __builtin_amdgcn_readfirstlane(rowstart[n + 1]);
  int len = p1i - p0i;
  int c0 = lane * 2;
  const int2v* pp = payload + p0i;
  float a00 = 0.f, a01 = 0.f, a10 = 0.f, a11 = 0.f, se0 = 0.f, se1 = 0.f;

#define K5_LD(soff) (*(const unsigned*)(hb8 + (size_t)(unsigned)(soff) + lane * 4))
#define K5_ACC(pl, w) { \
    float ex0 = bf2f((unsigned short)((unsigned)(pl).y & 0xffffu)); \
    float ex1 = bf2f((unsigned short)(((unsigned)(pl).y) >> 16)); \
    a00 = fmaf(ex0, __builtin_amdgcn_cvt_f32_fp8((int)(w), 0), a00); \
    a01 = fmaf(ex1, __builtin_amdgcn_cvt_f32_fp8((int)(w), 1), a01); \
    a10 = fmaf(ex0, __builtin_amdgcn_cvt_f32_fp8((int)(w), 2), a10); \
    a11 = fmaf(ex1, __builtin_amdgcn_cvt_f32_fp8((int)(w), 3), a11); \
    se0 += ex0; se1 += ex1; }

  if (len > 0) {
    int2v p0 = pp[0];
    int2v p1 = (len > 1) ? pp[1] : p0;
    int2v p2 = (len > 2) ? pp[2] : p0;
    int2v p3 = (len > 3) ? pp[3] : p0;
    unsigned h0 = K5_LD(p0.x), h1 = K5_LD(p1.x), h2 = K5_LD(p2.x), h3 = K5_LD(p3.x);
    int i = 0;
    for (; i + 7 < len; i += 4) {
      int2v q0 = pp[i + 4], q1 = pp[i + 5], q2 = pp[i + 6], q3 = pp[i + 7];
      unsigned g0 = K5_LD(q0.x), g1 = K5_LD(q1.x), g2 = K5_LD(q2.x), g3 = K5_LD(q3.x);
      K5_ACC(p0, h0); K5_ACC(p1, h1); K5_ACC(p2, h2); K5_ACC(p3, h3);
      p0 = q0; p1 = q1; p2 = q2; p3 = q3;
      h0 = g0; h1 = g1; h2 = g2; h3 = g3;
    }
    int r = len - i;           // 1..7
    K5_ACC(p0, h0);
    if (r > 1) K5_ACC(p1, h1);
    if (r > 2) K5_ACC(p2, h2);
    if (r > 3) K5_ACC(p3, h3);
    if (r > 4) {
      int rem = r - 4;         // 1..3
      int2v q0 = pp[i + 4];
      int2v q1 = (rem > 1) ? pp[i + 5] : q0;
      int2v q2 = (rem > 2) ? pp[i + 6] : q0;
      unsigned g0 = K5_LD(q0.x), g1 = K5_LD(q1.x), g2 = K5_LD(q2.x);
      K5_ACC(q0, g0);
      if (rem > 1) K5_ACC(q1, g1);
      if (rem > 2) K5_ACC(q2, g2);
    }
  }
#undef K5_LD
#undef K5_ACC

  float inv0 = 0.5f / (se0 + SMEPS);
  float inv1 = 0.5f / (se1 + SMEPS);
  float2 xv = *(const float2*)(x + (size_t)n * DD + c0);
  float v0 = a00 * inv0 + a01 * inv1 + bias[c0] + xv.x;
  float v1 = a10 * inv0 + a11 * inv1 + bias[c0 + 1] + xv.y;
  float s = v0 + v1, ss = v0 * v0 + v1 * v1;
#pragma unroll
  for (int o = 32; o > 0; o >>= 1) {
    s += __shfl_xor(s, o);
    ss += __shfl_xor(ss, o);
  }
  float mu = s * (1.f / 128.f);
  float var = ss * (1.f / 128.f) - mu * mu;
  float rstd = rsqrtf(var + LNEPS);
  float2 ov;
  ov.x = (v0 - mu) * rstd * gamma[c0] + beta[c0];
  ov.y = (v1 - mu) * rstd * gamma[c0 + 1] + beta[c0 + 1];
  *(float2*)(out + (size_t)n * CC + c0) = ov;
}

extern "C" void kernel_launch(void* const* d_in, const int* in_sizes, int n_in,
                              void* d_out, int out_size, void* d_ws, size_t ws_size,
                              hipStream_t stream) {
  const float* x        = (const float*)d_in[0];
  const int*   ei_raw   = (const int*)d_in[1];
  const float* edge_attr= (const float*)d_in[2];
  const float* W_ep     = (const float*)d_in[3];
  const float* b_ep     = (const float*)d_in[4];
  const float* W_lin    = (const float*)d_in[5];
  const float* att_src  = (const float*)d_in[6];
  const float* att_dst  = (const float*)d_in[7];
  const float* W_le     = (const float*)d_in[8];
  const float* att_edge = (const float*)d_in[9];
  const float* bias_gat = (const float*)d_in[10];
  const float* ln_gamma = (const float*)d_in[11];
  const float* ln_beta  = (const float*)d_in[12];

  char* ws = (char*)d_ws;
  unsigned char* hbuf8 = (unsigned char*)(ws + HB_OFF);
  float*    a_src  = (float*)(ws + ASRC_OFF);
  float*    a_dst  = (float*)(ws + ADST_OFF);
  float*    consts = (float*)(ws + CONST_OFF);
  int2v*    sd     = (int2v*)(ws + SD_OFF);
  int*      cnt    = (int*)(ws + CNT_OFF);
  int*      rowst  = (int*)(ws + ROW_OFF);
  int2v*    payload= (int2v*)(ws + PAY_OFF);
  unsigned short* wbT = (unsigned short*)(ws + WBT_OFF);
  int*      bsum   = (int*)(ws + BSUM_OFF);

  hipMemsetAsync(cnt, 0, (size_t)NN * 4, stream);
  kA_prep_convert<<<129 + CONV_B, 256, 0, stream>>>(W_lin, att_src, att_dst, W_le, att_edge,
                                                    W_ep, b_ep, ei_raw, consts, wbT, cnt, sd);
  k_scan1<<<SCAN_B, 256, 0, stream>>>(cnt, rowst, bsum);
  kB_scan_mfma<<<SCAN_B + K2_B, 256, 0, stream>>>(rowst, bsum, x, wbT, consts, hbuf8, a_src, a_dst);
  k34_edge<<<CONV_B, 256, 0, stream>>>(sd, rowst, edge_attr, a_src, a_dst, consts, payload);
  k5_fused<<<(NN + 3) / 4, 256, 0, stream>>>(rowst, payload, hbuf8, x, bias_gat, ln_gamma, ln_beta, (float*)d_out);
}

// Round 14
// 139.675 us; speedup vs baseline: 1.5462x; 1.0448x over previous
//
#include <hip/hip_runtime.h>
#include <hip/hip_bf16.h>

#define NN 50000
#define EE 800000
#define DD 128
#define HH 2
#define CC 128
#define HC 256
#define EDD 8

#define LEAKY 0.2f
#define SMEPS 1e-16f
#define LNEPS 1e-5f

#define SCAN_B 196   // ceil(NN/256)
#define CONV_B 3125  // EE/256
#define K2_B   782   // ceil(NN/64)
#define NPAD   50176 // SCAN_B*256

// ---- ws byte offsets ----
#define HB_OFF    0u           // fp8 h interleaved [n][c][head]: NN*256B = 12,800,000
#define ASRC_OFF  12800000u    // f32 a_src: NN*2*4 = 400,000
#define ADST_OFF  13200000u    // f32 a_dst         = 400,000
#define CONST_OFF 13600000u    // 530 floats (pad 4096)
#define SD_OFF    13604096u    // int2 sd: EE*8     = 6,400,000 (d|rank|xcd in .y)
#define CNT8_OFF  20004096u    // int32 cnt8[8][NPAD] = 1,605,632
#define ROW_OFF   21609728u    // int32 rowstart: NPAD+pad = 200,704
#define BASE8_OFF 21810432u    // int32 base8[8][NPAD] = 1,605,632
#define PAY_OFF   23416064u    // int2 payload: EE*8 = 6,400,000
#define WBT_OFF   29816064u    // bf16 wbT[256][128] = 65,536
#define BSUM_OFF  29881600u    // int32 bsum: 256
// total ~29.9 MB

typedef __attribute__((ext_vector_type(8))) short short8v;   // 8 bf16 (4 VGPR)
typedef __attribute__((ext_vector_type(4))) float float4v;   // MFMA acc
typedef __attribute__((ext_vector_type(2))) int int2v;

__device__ __forceinline__ float bf2f(unsigned short v) {
  return __uint_as_float(((unsigned)v) << 16);
}
__device__ __forceinline__ unsigned short f2bf(float f) {
  __hip_bfloat16 b = __float2bfloat16(f);
  return *reinterpret_cast<unsigned short*>(&b);
}

// KA: fused prep + convert.
// Block 0: attention-projection collapse -> consts. Blocks 1..128: W_lin -> bf16
// transposed wbT. Blocks 129..3253: edge_index normalize + XCD-LOCAL histogram.
// Workgroup-scope atomics stay in the issuing XCD's L2 (no memory-side RMW, no
// HBM write-through); 8 replicas indexed by s_getreg(HW_REG_XCC_ID)&7.
// sd.y packs d(16) | rank(13) | xcd(3).
__global__ __launch_bounds__(256) void kA_prep_convert(const float* __restrict__ W_lin,
                                                       const float* __restrict__ att_src,
                                                       const float* __restrict__ att_dst,
                                                       const float* __restrict__ W_le,
                                                       const float* __restrict__ att_edge,
                                                       const float* __restrict__ W_ep,
                                                       const float* __restrict__ b_ep,
                                                       const int* __restrict__ ei_raw,
                                                       float* __restrict__ consts,
                                                       unsigned short* __restrict__ wbT,
                                                       int* __restrict__ cnt8,
                                                       int2v* __restrict__ sd) {
  int b = blockIdx.x, tid = threadIdx.x;
  if (b == 0) {
    __shared__ float vlds[HH * DD];
    int h = tid >> 7, d = tid & 127;
    const float* as = att_src + h * CC;
    const float* ad = att_dst + h * CC;
    const float* ae = att_edge + h * CC;
    float us = 0.f, ud = 0.f, vv = 0.f;
    for (int c = 0; c < CC; ++c) {
      float wl = W_lin[d * HC + h * CC + c];
      float we = W_le[d * HC + h * CC + c];
      us += wl * as[c]; ud += wl * ad[c]; vv += we * ae[c];
    }
    consts[h * 128 + d] = us;
    consts[256 + h * 128 + d] = ud;
    vlds[h * 128 + d] = vv;
    __syncthreads();
    if (tid < 16) {
      int hh = tid >> 3, k = tid & 7;
      float w = 0.f;
      for (int dd2 = 0; dd2 < DD; ++dd2) w += W_ep[k * DD + dd2] * vlds[hh * 128 + dd2];
      consts[512 + hh * 8 + k] = w;
    }
    if (tid < 2) {
      float ce = 0.f;
      for (int dd2 = 0; dd2 < DD; ++dd2) ce += b_ep[dd2] * vlds[tid * 128 + dd2];
      consts[528 + tid] = ce;
    }
  } else if (b <= 128) {
    int i = (b - 1) * 256 + tid;           // i = k*256 + c, exactly 32768
    int k = i >> 8, c = i & 255;
    wbT[c * DD + k] = f2bf(W_lin[i]);
  } else {
    int lane = threadIdx.x & 63;
    int probe = ei_raw[2 * lane + 1];
    bool is64 = (__ballot(probe != 0) == 0ull);
    int xcd = __builtin_amdgcn_s_getreg((20) | (0 << 6) | ((32 - 1) << 11)) & 7;
    int i = (b - 129) * 256 + tid;         // exact: CONV_B*256 = EE
    int s, d;
    if (is64) { s = ei_raw[2 * i]; d = ei_raw[2 * (EE + i)]; }
    else      { s = ei_raw[i];     d = ei_raw[EE + i]; }
    int rk = __hip_atomic_fetch_add(&cnt8[xcd * NPAD + d], 1,
                                    __ATOMIC_RELAXED, __HIP_MEMORY_SCOPE_WORKGROUP);
    int2v v; v.x = s; v.y = d | (rk << 16) | (xcd << 29);
    sd[i] = v;
  }
}

// K_scan1: per-block scan. Reads 8 XCD replicas, totals them, intra-block
// exclusive scan -> rowstart; also emits per-XCD running bases into base8.
__global__ __launch_bounds__(256) void k_scan1(const int* __restrict__ cnt8,
                                               int* __restrict__ rowstart,
                                               int* __restrict__ base8,
                                               int* __restrict__ bsum) {
  __shared__ int sp[256];
  int t = threadIdx.x, b = blockIdx.x;
  int n = b * 256 + t;
  int c[8];
  int tot = 0;
#pragma unroll
  for (int r = 0; r < 8; ++r) {
    c[r] = (n < NN) ? cnt8[r * NPAD + n] : 0;
    tot += c[r];
  }
  sp[t] = tot;
  __syncthreads();
  for (int off = 1; off < 256; off <<= 1) {
    int u = (t >= off) ? sp[t - off] : 0;
    __syncthreads();
    sp[t] += u;
    __syncthreads();
  }
  int intra = sp[t] - tot;
  if (n < NN) {
    rowstart[n] = intra;
    int run = intra;
#pragma unroll
    for (int r = 0; r < 8; ++r) { base8[r * NPAD + n] = run; run += c[r]; }
  }
  if (t == 255) bsum[b] = sp[255];
}

// KB: fused scan23 + MFMA node projection. Blocks 0..195: finish prefix scan
// (apply block offset to rowstart AND the 8 base8 replicas). Blocks 196..977:
// h = x @ W_lin (MFMA bf16), fused a_src/a_dst, fp8 e4m3 epilogue (256 B/node).
__global__ __launch_bounds__(256) void kB_scan_mfma(int* __restrict__ rowstart,
                                                    const int* __restrict__ bsum,
                                                    int* __restrict__ base8,
                                                    const float* __restrict__ x,
                                                    const unsigned short* __restrict__ wbT,
                                                    const float* __restrict__ consts,
                                                    unsigned char* __restrict__ hbuf8,
                                                    float* __restrict__ a_src,
                                                    float* __restrict__ a_dst) {
  __shared__ unsigned short xs[64 * 256];   // 32KB (scan part uses first 1KB)
  int tid = threadIdx.x;

  if (blockIdx.x < SCAN_B) {
    int* sp = (int*)xs;
    int t = tid, b = blockIdx.x;
    int v = (t < SCAN_B) ? bsum[t] : 0;
    sp[t] = v;
    __syncthreads();
    for (int off = 1; off < 256; off <<= 1) {
      int u = (t >= off) ? sp[t - off] : 0;
      __syncthreads();
      sp[t] += u;
      __syncthreads();
    }
    int boff = (b == 0) ? 0 : sp[b - 1];
    int n = b * 256 + t;
    if (n < NN) {
      rowstart[n] += boff;
#pragma unroll
      for (int r = 0; r < 8; ++r) base8[r * NPAD + n] += boff;
    }
    if (n == NN) rowstart[NN] = EE;
    return;
  }

  int n0 = (blockIdx.x - SCAN_B) * 64;
  int r = tid >> 2, q = tid & 3;
  int n = n0 + r;
  bool valid = (n < NN);

  float xv[32];
  const float4* xp = (const float4*)(x + (size_t)n * DD + q * 32);
#pragma unroll
  for (int j = 0; j < 8; ++j) {
    float4 v = valid ? xp[j] : make_float4(0.f, 0.f, 0.f, 0.f);
    xv[j * 4 + 0] = v.x; xv[j * 4 + 1] = v.y; xv[j * 4 + 2] = v.z; xv[j * 4 + 3] = v.w;
  }
  float ps0 = 0.f, ps1 = 0.f, pd0 = 0.f, pd1 = 0.f;
#pragma unroll
  for (int j = 0; j < 32; j += 4) {
    float4 u0 = *(const float4*)(consts +   0 + q * 32 + j);
    float4 u1 = *(const float4*)(consts + 128 + q * 32 + j);
    float4 v0 = *(const float4*)(consts + 256 + q * 32 + j);
    float4 v1 = *(const float4*)(consts + 384 + q * 32 + j);
    ps0 += xv[j] * u0.x + xv[j+1] * u0.y + xv[j+2] * u0.z + xv[j+3] * u0.w;
    ps1 += xv[j] * u1.x + xv[j+1] * u1.y + xv[j+2] * u1.z + xv[j+3] * u1.w;
    pd0 += xv[j] * v0.x + xv[j+1] * v0.y + xv[j+2] * v0.z + xv[j+3] * v0.w;
    pd1 += xv[j] * v1.x + xv[j+1] * v1.y + xv[j+2] * v1.z + xv[j+3] * v1.w;
  }
#pragma unroll
  for (int off = 1; off < 4; off <<= 1) {
    ps0 += __shfl_xor(ps0, off); ps1 += __shfl_xor(ps1, off);
    pd0 += __shfl_xor(pd0, off); pd1 += __shfl_xor(pd1, off);
  }
  if (q == 0 && valid) {
    *(float2*)(a_src + n * 2) = make_float2(ps0, ps1);
    *(float2*)(a_dst + n * 2) = make_float2(pd0, pd1);
  }

#pragma unroll
  for (int ci = 0; ci < 4; ++ci) {
    union { short8v v; unsigned short u[8]; } pk;
#pragma unroll
    for (int j = 0; j < 8; ++j) pk.u[j] = f2bf(xv[ci * 8 + j]);
    unsigned byte = r * 256 + (q * 4 + ci) * 16;
    byte ^= (r & 7) << 4;
    *(short8v*)((char*)xs + byte) = pk.v;
  }

  int wave = tid >> 6, l = tid & 63;
  int wc = wave * 64;
  int lr = l & 15, lg = l >> 4;
  short8v bfr[4][4];
#pragma unroll
  for (int ct = 0; ct < 4; ++ct) {
    int col = wc + ct * 16 + lr;
#pragma unroll
    for (int kt = 0; kt < 4; ++kt)
      bfr[ct][kt] = *(const short8v*)(wbT + (size_t)col * DD + kt * 32 + lg * 8);
  }

  __syncthreads();

  float4v acc[4][4];
#pragma unroll
  for (int rt = 0; rt < 4; ++rt)
#pragma unroll
    for (int ct = 0; ct < 4; ++ct) acc[rt][ct] = (float4v){0.f, 0.f, 0.f, 0.f};

#pragma unroll
  for (int kt = 0; kt < 4; ++kt) {
    short8v afr[4];
#pragma unroll
    for (int rt = 0; rt < 4; ++rt) {
      int row = rt * 16 + lr;
      unsigned byte = row * 256 + kt * 64 + lg * 16;
      byte ^= (row & 7) << 4;
      afr[rt] = *(const short8v*)((const char*)xs + byte);
    }
#pragma unroll
    for (int rt = 0; rt < 4; ++rt)
#pragma unroll
      for (int ct = 0; ct < 4; ++ct)
        acc[rt][ct] = __builtin_amdgcn_mfma_f32_16x16x32_bf16(afr[rt], bfr[ct][kt], acc[rt][ct], 0, 0, 0);
  }

  // epilogue: acc -> LDS bf16 (interleaved, row-swizzled) -> fp8 pack -> 16B stores
  __syncthreads();
#pragma unroll
  for (int rt = 0; rt < 4; ++rt) {
#pragma unroll
    for (int j = 0; j < 4; ++j) {
      int row = rt * 16 + lg * 4 + j;
#pragma unroll
      for (int ct = 0; ct < 4; ++ct) {
        int col = wc + ct * 16 + lr;
        int idx2 = ((col & 127) << 1) | (col >> 7);
        unsigned o = (unsigned)idx2 * 2;
        unsigned byte = row * 512 + (o ^ ((((unsigned)(row & 7) ^ ((o >> 7) & 3))) << 4));
        *(unsigned short*)((char*)xs + byte) = f2bf(acc[rt][ct][j]);
      }
    }
  }
  __syncthreads();
  {
    int r2 = tid >> 2, q2 = tid & 3;
    int n2 = n0 + r2;
    if (n2 < NN) {
#pragma unroll
      for (int kk = 0; kk < 4; ++kk) {
        unsigned u4[4];
#pragma unroll
        for (int t2 = 0; t2 < 2; ++t2) {
          int k = kk * 2 + t2;
          unsigned o = q2 * 128 + k * 16;
          unsigned byte = r2 * 512 + (o ^ ((((unsigned)(r2 & 7) ^ ((o >> 7) & 3))) << 4));
          short8v v = *(short8v*)((char*)xs + byte);
          unsigned ua = __builtin_amdgcn_cvt_pk_fp8_f32(bf2f((unsigned short)v[0]), bf2f((unsigned short)v[1]), 0u, false);
          ua = __builtin_amdgcn_cvt_pk_fp8_f32(bf2f((unsigned short)v[2]), bf2f((unsigned short)v[3]), ua, true);
          unsigned ub = __builtin_amdgcn_cvt_pk_fp8_f32(bf2f((unsigned short)v[4]), bf2f((unsigned short)v[5]), 0u, false);
          ub = __builtin_amdgcn_cvt_pk_fp8_f32(bf2f((unsigned short)v[6]), bf2f((unsigned short)v[7]), ub, true);
          u4[t2 * 2] = ua; u4[t2 * 2 + 1] = ub;
        }
        uint4 w4 = make_uint4(u4[0], u4[1], u4[2], u4[3]);
        *(uint4*)(hbuf8 + (size_t)n2 * 256 + q2 * 64 + kk * 16) = w4;
      }
    }
  }
}

// K34: edge pass, zero data atomics. score -> leaky -> ex=exp(score).
// pos = base8[xcd][d] + rank (per-XCD segment within the node's CSR range).
__global__ __launch_bounds__(256) void k34_edge(const int2v* __restrict__ sd,
                                                const int* __restrict__ base8,
                                                const float* __restrict__ edge_attr,
                                                const float* __restrict__ a_src,
                                                const float* __restrict__ a_dst,
                                                const float* __restrict__ consts,
                                                int2v* __restrict__ payload) {
  int e = blockIdx.x * 256 + threadIdx.x;   // grid exact: EE/256
  int2v sdv = sd[e];
  int s = sdv.x;
  unsigned y = (unsigned)sdv.y;
  int d = (int)(y & 0xFFFFu);
  int rk = (int)((y >> 16) & 0x1FFFu);
  int xcd = (int)(y >> 29);
  float4 ea0 = *(const float4*)(edge_attr + (size_t)e * 8);
  float4 ea1 = *(const float4*)(edge_attr + (size_t)e * 8 + 4);
  float2 asv = *(const float2*)(a_src + s * 2);
  float2 adv = *(const float2*)(a_dst + d * 2);
  const float* w0 = consts + 512;
  const float* w1 = consts + 520;
  float sc0 = asv.x + adv.x + consts[528]
            + ea0.x * w0[0] + ea0.y * w0[1] + ea0.z * w0[2] + ea0.w * w0[3]
            + ea1.x * w0[4] + ea1.y * w0[5] + ea1.z * w0[6] + ea1.w * w0[7];
  float sc1 = asv.y + adv.y + consts[529]
            + ea0.x * w1[0] + ea0.y * w1[1] + ea0.z * w1[2] + ea0.w * w1[3]
            + ea1.x * w1[4] + ea1.y * w1[5] + ea1.z * w1[6] + ea1.w * w1[7];
  sc0 = (sc0 >= 0.f) ? sc0 : LEAKY * sc0;
  sc1 = (sc1 >= 0.f) ? sc1 : LEAKY * sc1;
  float ex0 = __expf(sc0);
  float ex1 = __expf(sc1);
  unsigned pk = (unsigned)f2bf(ex0) | ((unsigned)f2bf(ex1) << 16);
  int pos = base8[xcd * NPAD + d] + rk;
  int2v pv; pv.x = s << 8; pv.y = (int)pk;   // s<<8 = byte offset of fp8 row
  payload[pos] = pv;
}

// K5: wave per node. CSR walk, depth-4 batched pipeline. Per edge each lane
// reads ONE uint (4 fp8: h0[c],h1[c],h0[c+1],h1[c+1]); HW v_cvt_f32_fp8 decode.
__global__ __launch_bounds__(256) void k5_fused(const int* __restrict__ rowstart,
                                                const int2v* __restrict__ payload,
                                                const unsigned char* __restrict__ hb8,
                                                const float* __restrict__ x,
                                                const float* __restrict__ bias,
                                                const float* __restrict__ gamma,
                                                const float* __restrict__ beta,
                                                float* __restrict__ out) {
  int n = blockIdx.x * 4 + (threadIdx.x >> 6);
  int lane = threadIdx.x & 63;
  if (n >= NN) return;
  int p0i = __builtin_amdgcn_readfirstlane(rowstart[n]);
  int p1i = __builtin_amdgcn_readfirstlane(rowstart[n + 1]);
  int len = p1i - p0i;
  int c0 = lane * 2;
  const int2v* pp = payload + p0i;
  float a00 = 0.f, a01 = 0.f, a10 = 0.f, a11 = 0.f, se0 = 0.f, se1 = 0.f;

#define K5_LD(soff) (*(const unsigned*)(hb8 + (size_t)(unsigned)(soff) + lane * 4))
#define K5_ACC(pl, w) { \
    float ex0 = bf2f((unsigned short)((unsigned)(pl).y & 0xffffu)); \
    float ex1 = bf2f((unsigned short)(((unsigned)(pl).y) >> 16)); \
    a00 = fmaf(ex0, __builtin_amdgcn_cvt_f32_fp8((int)(w), 0), a00); \
    a01 = fmaf(ex1, __builtin_amdgcn_cvt_f32_fp8((int)(w), 1), a01); \
    a10 = fmaf(ex0, __builtin_amdgcn_cvt_f32_fp8((int)(w), 2), a10); \
    a11 = fmaf(ex1, __builtin_amdgcn_cvt_f32_fp8((int)(w), 3), a11); \
    se0 += ex0; se1 += ex1; }

  if (len > 0) {
    int2v p0 = pp[0];
    int2v p1 = (len > 1) ? pp[1] : p0;
    int2v p2 = (len > 2) ? pp[2] : p0;
    int2v p3 = (len > 3) ? pp[3] : p0;
    unsigned h0 = K5_LD(p0.x), h1 = K5_LD(p1.x), h2 = K5_LD(p2.x), h3 = K5_LD(p3.x);
    int i = 0;
    for (; i + 7 < len; i += 4) {
      int2v q0 = pp[i + 4], q1 = pp[i + 5], q2 = pp[i + 6], q3 = pp[i + 7];
      unsigned g0 = K5_LD(q0.x), g1 = K5_LD(q1.x), g2 = K5_LD(q2.x), g3 = K5_LD(q3.x);
      K5_ACC(p0, h0); K5_ACC(p1, h1); K5_ACC(p2, h2); K5_ACC(p3, h3);
      p0 = q0; p1 = q1; p2 = q2; p3 = q3;
      h0 = g0; h1 = g1; h2 = g2; h3 = g3;
    }
    int r = len - i;           // 1..7
    K5_ACC(p0, h0);
    if (r > 1) K5_ACC(p1, h1);
    if (r > 2) K5_ACC(p2, h2);
    if (r > 3) K5_ACC(p3, h3);
    if (r > 4) {
      int rem = r - 4;         // 1..3
      int2v q0 = pp[i + 4];
      int2v q1 = (rem > 1) ? pp[i + 5] : q0;
      int2v q2 = (rem > 2) ? pp[i + 6] : q0;
      unsigned g0 = K5_LD(q0.x), g1 = K5_LD(q1.x), g2 = K5_LD(q2.x);
      K5_ACC(q0, g0);
      if (rem > 1) K5_ACC(q1, g1);
      if (rem > 2) K5_ACC(q2, g2);
    }
  }
#undef K5_LD
#undef K5_ACC

  float inv0 = 0.5f / (se0 + SMEPS);
  float inv1 = 0.5f / (se1 + SMEPS);
  float2 xv = *(const float2*)(x + (size_t)n * DD + c0);
  float v0 = a00 * inv0 + a01 * inv1 + bias[c0] + xv.x;
  float v1 = a10 * inv0 + a11 * inv1 + bias[c0 + 1] + xv.y;
  float s = v0 + v1, ss = v0 * v0 + v1 * v1;
#pragma unroll
  for (int o = 32; o > 0; o >>= 1) {
    s += __shfl_xor(s, o);
    ss += __shfl_xor(ss, o);
  }
  float mu = s * (1.f / 128.f);
  float var = ss * (1.f / 128.f) - mu * mu;
  float rstd = rsqrtf(var + LNEPS);
  float2 ov;
  ov.x = (v0 - mu) * rstd * gamma[c0] + beta[c0];
  ov.y = (v1 - mu) * rstd * gamma[c0 + 1] + beta[c0 + 1];
  *(float2*)(out + (size_t)n * CC + c0) = ov;
}

extern "C" void kernel_launch(void* const* d_in, const int* in_sizes, int n_in,
                              void* d_out, int out_size, void* d_ws, size_t ws_size,
                              hipStream_t stream) {
  const float* x        = (const float*)d_in[0];
  const int*   ei_raw   = (const int*)d_in[1];
  const float* edge_attr= (const float*)d_in[2];
  const float* W_ep     = (const float*)d_in[3];
  const float* b_ep     = (const float*)d_in[4];
  const float* W_lin    = (const float*)d_in[5];
  const float* att_src  = (const float*)d_in[6];
  const float* att_dst  = (const float*)d_in[7];
  const float* W_le     = (const float*)d_in[8];
  const float* att_edge = (const float*)d_in[9];
  const float* bias_gat = (const float*)d_in[10];
  const float* ln_gamma = (const float*)d_in[11];
  const float* ln_beta  = (const float*)d_in[12];

  char* ws = (char*)d_ws;
  unsigned char* hbuf8 = (unsigned char*)(ws + HB_OFF);
  float*    a_src  = (float*)(ws + ASRC_OFF);
  float*    a_dst  = (float*)(ws + ADST_OFF);
  float*    consts = (float*)(ws + CONST_OFF);
  int2v*    sd     = (int2v*)(ws + SD_OFF);
  int*      cnt8   = (int*)(ws + CNT8_OFF);
  int*      rowst  = (int*)(ws + ROW_OFF);
  int*      base8  = (int*)(ws + BASE8_OFF);
  int2v*    payload= (int2v*)(ws + PAY_OFF);
  unsigned short* wbT = (unsigned short*)(ws + WBT_OFF);
  int*      bsum   = (int*)(ws + BSUM_OFF);

  hipMemsetAsync(cnt8, 0, (size_t)8 * NPAD * 4, stream);
  kA_prep_convert<<<129 + CONV_B, 256, 0, stream>>>(W_lin, att_src, att_dst, W_le, att_edge,
                                                    W_ep, b_ep, ei_raw, consts, wbT, cnt8, sd);
  k_scan1<<<SCAN_B, 256, 0, stream>>>(cnt8, rowst, base8, bsum);
  kB_scan_mfma<<<SCAN_B + K2_B, 256, 0, stream>>>(rowst, bsum, base8, x, wbT, consts, hbuf8, a_src, a_dst);
  k34_edge<<<CONV_B, 256, 0, stream>>>(sd, base8, edge_attr, a_src, a_dst, consts, payload);
  k5_fused<<<(NN + 3) / 4, 256, 0, stream>>>(rowst, payload, hbuf8, x, bias_gat, ln_gamma, ln_beta, (float*)d_out);
}